// Round 7
// baseline (1919.550 us; speedup 1.0000x reference)
//
#include <hip/hip_runtime.h>
#include <hip/hip_bf16.h>
#include <math.h>

#define VOL 729000
#define SL  8100
#define RW  90

typedef __attribute__((ext_vector_type(8))) short s8v;
typedef __attribute__((ext_vector_type(16))) float f32x16;

union FragU { s8v s; uint u[4]; };

__device__ __constant__ int c_o1[12][3] = {
  {0,0,-2},{0,-2,0},{0,-2,0},{0,0,2},{0,0,2},{2,0,0},{2,0,0},{2,0,0},{0,2,0},{0,2,0},{0,2,0},{0,2,0}
};
__device__ __constant__ int c_o2[12][3] = {
  {-2,0,0},{-2,0,0},{0,0,-2},{-2,0,0},{0,-2,0},{0,0,-2},{0,-2,0},{0,0,2},{-2,0,0},{0,0,-2},{0,0,2},{2,0,0}
};

__device__ __forceinline__ int clampi(int v, int lo, int hi){ return v<lo?lo:(v>hi?hi:v); }

typedef __attribute__((address_space(3))) uint lds_uint;
typedef __attribute__((address_space(1))) uint glb_uint;
__device__ __forceinline__ void gl_lds16(const ushort* g, ushort* l) {
  // per-lane global src gather; LDS dst = wave-uniform base + lane*16B
  __builtin_amdgcn_global_load_lds((const glb_uint*)g, (lds_uint*)l, 16, 0, 0);
}

__global__ void diff2z_kernel(const float* __restrict__ img, float* __restrict__ out) {
  int idx = blockIdx.x*256 + threadIdx.x;
  if (idx >= 2*12*VOL) return;
  int vox = idx % VOL; int ct = idx / VOL; int t = ct % 12, b = ct / 12;
  int z = vox / SL; int r = vox % SL; int y = r / RW; int x = r % RW;
  const float* im = img + (size_t)b*VOL;
  int o1z=c_o1[t][0], o1y=c_o1[t][1], o1x=c_o1[t][2];
  int o2z=c_o2[t][0], o2y=c_o2[t][1], o2x=c_o2[t][2];
  int y1 = clampi(y+o1y,0,89), x1 = clampi(x+o1x,0,89);
  int y2 = clampi(y+o2y,0,89), x2 = clampi(x+o2x,0,89);
  float s = 0.f;
  #pragma unroll
  for (int d=-2; d<=2; ++d) {
    int zz = clampi(z+d,0,89);
    int z1 = clampi(zz+o1z,0,89), z2 = clampi(zz+o2z,0,89);
    float dv = im[z1*SL+y1*RW+x1] - im[z2*SL+y2*RW+x2];
    s += dv*dv;
  }
  out[idx] = s;
}

__global__ void boxy_kernel(const float* __restrict__ in, float* __restrict__ out) {
  int idx = blockIdx.x*256 + threadIdx.x;
  if (idx >= 2*12*VOL) return;
  int vox = idx % VOL; int bc = idx / VOL;
  int z = vox / SL; int r = vox % SL; int y = r / RW; int x = r % RW;
  const float* p = in + (size_t)bc*VOL + (size_t)z*SL + x;
  float s = 0.f;
  #pragma unroll
  for (int d=-2; d<=2; ++d) { int yc = clampi(y+d,0,89); s += p[yc*RW]; }
  out[idx] = s;
}

__global__ void boxxmin_kernel(const float* __restrict__ in, float* __restrict__ outPre,
                               float* __restrict__ mvsum) {
  __shared__ float red;
  if (threadIdx.x == 0) red = 0.f;
  __syncthreads();
  int idx = blockIdx.x*256 + threadIdx.x;
  float mv = 0.f;
  if (idx < 2*VOL) {
    int b = idx / VOL; int vox = idx % VOL;
    int z = vox / SL; int r = vox % SL; int y = r / RW; int x = r % RW;
    const float* base = in + (size_t)b*12*VOL + (size_t)z*SL + (size_t)y*RW;
    float s[12]; float mn = 3.4e38f;
    #pragma unroll
    for (int c=0;c<12;++c) {
      const float* pc = base + (size_t)c*VOL;
      float t = 0.f;
      #pragma unroll
      for (int d=-2;d<=2;++d) { int xc = clampi(x+d,0,89); t += pc[xc]; }
      t *= (1.0f/125.0f);
      s[c] = t; mn = fminf(mn, t);
    }
    float* ob = outPre + (size_t)b*12*VOL + vox;
    #pragma unroll
    for (int c=0;c<12;++c) { float pre = s[c]-mn; ob[(size_t)c*VOL] = pre; mv += pre; }
    mv *= (1.0f/12.0f);
  }
  #pragma unroll
  for (int o=32;o;o>>=1) mv += __shfl_xor(mv, o);
  if ((threadIdx.x & 63)==0 && mv != 0.f) atomicAdd(&red, mv);
  __syncthreads();
  if (threadIdx.x==0) atomicAdd(mvsum, red);
}

__global__ void finalize_kernel(const float* __restrict__ pre, float* __restrict__ out,
                                const float* __restrict__ mvsum) {
  int idx = blockIdx.x*256 + threadIdx.x;
  if (idx >= 2*VOL) return;
  int b = idx / VOL; int vox = idx % VOL;
  const float* base = pre + (size_t)b*12*VOL + vox;
  float* ob = out + (size_t)b*12*VOL + vox;
  float s[12]; float mv = 0.f;
  #pragma unroll
  for (int c=0;c<12;++c) { s[c] = base[(size_t)c*VOL]; mv += s[c]; }
  mv *= (1.0f/12.0f);
  float mm = *mvsum * (1.0f/1458000.0f);
  float mvc = fminf(fmaxf(mv, mm*0.001f), mm*1000.0f);
  float inv = 1.0f / mvc;
  #pragma unroll
  for (int c=0;c<12;++c) ob[(size_t)c*VOL] = __expf(-s[c]*inv);
}

template<int P>
__global__ __launch_bounds__(64) void pack_kernel(const float* __restrict__ mind,
                                                  ushort* __restrict__ out) {
  constexpr int NG=90/P, N=NG*NG*NG, C=12*P*P*P;
  int d = blockIdx.x;
  int b = d / N, n = d % N;
  int gz = n/(NG*NG), rn = n%(NG*NG), gy = rn/NG, gx = rn%NG;
  const float* mf = mind + (size_t)b*12*VOL + (size_t)gz*P*SL + (size_t)gy*P*RW + gx*P;
  int lane = threadIdx.x;
  float ss = 0.f;
  for (int j = lane; j < C; j += 64) {
    int c = j/(P*P*P); int r = j%(P*P*P); int dz = r/(P*P); int r2 = r%(P*P); int dy = r2/P; int dx = r2%P;
    float v = mf[(size_t)c*VOL + dz*SL + dy*RW + dx];
    ss += v*v;
  }
  #pragma unroll
  for (int o=32;o;o>>=1) ss += __shfl_xor(ss, o);
  float inv = 1.0f/fmaxf(sqrtf(ss), 1e-12f);
  ushort* ob = out + (size_t)d*C;
  for (int j = lane; j < C; j += 64) {
    int c = j/(P*P*P); int r = j%(P*P*P); int dz = r/(P*P); int r2 = r%(P*P); int dy = r2/P; int dx = r2%P;
    float v = mf[(size_t)c*VOL + dz*SL + dy*RW + dx] * inv;
    __hip_bfloat16 h = __float2bfloat16(v);
    ob[j] = *(ushort*)&h;
  }
}

// 32x32x16 frag-native LDS loss. Block = (b, mz, gy, j), gz = mz-R+j.
// Per phase (KB k-steps): stage A tiles (KB) + B tiles (nch*KB) via
// global_load_lds (frag-order: lane*16B). Per k-step a wave reads ONE A-frag
// and CPW B-frags for CPW MFMAs. K split across wave groups (KSPLIT), partial
// accs combined through LDS at the end. Output D: col(m)=lane&31,
// row(x)=(reg&3)+8*(reg>>2)+4*(lane>>5).
template<int P, int R, int KB, int KSPLIT, int CPW, int NCHMAX>
__global__ __launch_bounds__(256) void loss_kernel(
    const ushort* __restrict__ pkF, const ushort* __restrict__ pkM,
    float* __restrict__ sumG, float* __restrict__ alnG) {
  constexpr int NG = 90/P, N = NG*NG*NG, C = 12*P*P*P;
  constexpr int KS16 = C/16, TAIL = C%16;           // TAIL in {4,12}
  constexpr int KSTEPS = KS16 + (TAIL ? 1 : 0);
  constexpr int NPH = (KSTEPS + KB - 1)/KB;
  constexpr int NW = 4, WZ = 2*R+1;
  constexpr int WPK = NW/KSPLIT;
  constexpr int TILES = KB*(1+NCHMAX);
  constexpr int V0 = TAIL >= 8 ? 8 : TAIL;
  constexpr int V1 = TAIL >= 8 ? TAIL-8 : 0;
  static_assert(NCHMAX*32 >= WZ*NG, "chunk capacity");
  static_assert(CPW*WPK >= NCHMAX, "chunk coverage");

  __shared__ float sumS[32];
  __shared__ __align__(16) ushort bP[2][TILES*512];

  int nwg = gridDim.x;
  int q = nwg >> 3, r8 = nwg & 7;
  int xcd = blockIdx.x & 7, sidx = blockIdx.x >> 3;
  int lid = (xcd < r8 ? xcd*(q+1) : r8*(q+1) + (xcd - r8)*q) + sidx;
  int j = lid % WZ; int t1 = lid / WZ;
  int gy = t1 % NG; t1 /= NG;
  int mz = t1 % NG; int b = t1 / NG;
  int gz = mz - R + j;
  if (gz < 0 || gz >= NG) return;

  int tid = threadIdx.x; int lane = tid & 63; int wv = tid >> 6;
  int half = lane >> 5; int kh8 = half*8;
  int kq = wv / WPK;            // k-slot of this wave
  int cw = wv % WPK;            // chunk base

  for (int i = tid; i < 32; i += 256) sumS[i] = 0.f;

  size_t baseF = ((size_t)b*N + ((size_t)gz*NG + gy)*NG) * C;
  int arow = lane & 31; if (arow > NG-1) arow = NG-1;
  const ushort* aLane = pkF + baseF + (size_t)arow*C + kh8;

  int y0 = max(gy-R,0), y1 = min(gy+R,NG-1);
  int wy = y1-y0+1;
  int Ms = wy*NG;
  int nch = (Ms + 31) >> 5;
  const ushort* sliceM = pkM + ((size_t)b*N + ((size_t)mz*NG + y0)*NG) * C;
  float* lineSum = sumG + (size_t)b*N + ((size_t)gz*NG + gy)*NG;
  float* lineAln = alnG + (size_t)b*N + ((size_t)gz*NG + gy)*NG;

  auto stage = [&](int ph, int bufi) {
    ushort* dst = bP[bufi];
    int ks0 = ph*KB;
    int tiles = KB*(1+nch);
    for (int i = wv; i < tiles; i += NW) {
      int s, c;
      if (i < KB) { s = i; c = -1; }
      else { int bi = i - KB; c = bi/KB; s = bi - c*KB; }
      int ks = ks0 + s;
      if (ks >= KSTEPS) continue;
      const ushort* src;
      if (c < 0) src = aLane + ks*16;
      else {
        int di = c*32 + (lane & 31); if (di > Ms-1) di = Ms-1;
        src = sliceM + (size_t)di*C + ks*16 + kh8;
      }
      gl_lds16(src, dst + i*512);
    }
  };

  f32x16 acc[CPW];
  #pragma unroll
  for (int t=0;t<CPW;++t)
    acc[t] = (f32x16){0.f,0.f,0.f,0.f,0.f,0.f,0.f,0.f,0.f,0.f,0.f,0.f,0.f,0.f,0.f,0.f};

  stage(0, 0);
  __syncthreads();
  for (int p = 0; p < NPH; ++p) {
    int bufi = p & 1;
    if (p + 1 < NPH) stage(p+1, bufi^1);
    const ushort* buf = bP[bufi];
    #pragma unroll
    for (int s = 0; s < KB; ++s) {
      int ks = p*KB + s;
      if (ks >= KSTEPS) break;
      if (KSPLIT > 1 && (ks % KSPLIT) != kq) continue;
      FragU fa; fa.s = *(const s8v*)(buf + s*512 + lane*8);
      if (TAIL && ks == KS16) {
        int v = half ? V1 : V0;
        if (v < 8) { fa.u[2]=0; fa.u[3]=0; }
        if (v < 4) { fa.u[0]=0; fa.u[1]=0; }
      }
      #pragma unroll
      for (int t = 0; t < CPW; ++t) {
        int c = cw + t*WPK;
        if (c < nch) {
          FragU fb; fb.s = *(const s8v*)(buf + (KB + c*KB + s)*512 + lane*8);
          if (TAIL && ks == KS16) {
            int v = half ? V1 : V0;
            if (v < 8) { fb.u[2]=0; fb.u[3]=0; }
            if (v < 4) { fb.u[0]=0; fb.u[1]=0; }
          }
          acc[t] = __builtin_amdgcn_mfma_f32_32x32x16_bf16(fa.s, fb.s, acc[t], 0, 0, 0);
        }
      }
    }
    __syncthreads();
  }

  if constexpr (KSPLIT > 1) {
    float* cb = (float*)bP;
    if (kq > 0) {
      int base = (((kq-1)*WPK + cw)*CPW*64 + lane)*16;
      #pragma unroll
      for (int t=0;t<CPW;++t)
        #pragma unroll
        for (int r=0;r<16;++r) cb[base + t*64*16 + r] = acc[t][r];
    }
    __syncthreads();
    if (kq == 0) {
      for (int k2 = 1; k2 < KSPLIT; ++k2) {
        int base = (((k2-1)*WPK + cw)*CPW*64 + lane)*16;
        #pragma unroll
        for (int t=0;t<CPW;++t)
          #pragma unroll
          for (int r=0;r<16;++r) acc[t][r] += cb[base + t*64*16 + r];
      }
    }
  }

  if (kq == 0) {
    float e[16];
    #pragma unroll
    for (int r=0;r<16;++r) e[r] = 0.f;
    #pragma unroll
    for (int t=0;t<CPW;++t) {
      int c = cw + t*WPK;
      if (c < nch) {
        int mu = c*32 + (lane&31); bool vm = mu < Ms;
        int mus = vm ? mu : Ms-1;
        int myq = mus/NG; int my = y0 + myq; int mx = mus - myq*NG;
        bool alnRow = (mz==gz) && (my==gy) && vm;
        #pragma unroll
        for (int r=0;r<16;++r) {
          int x = (r&3) + 8*(r>>2) + 4*half;
          float sim = acc[t][r];
          bool ok = vm && (x < NG) && (mx-x<=R) && (x-mx<=R);
          if (ok) e[r] += __expf(sim);
          if (alnRow && mx==x) lineAln[x] = sim;
        }
      }
    }
    #pragma unroll
    for (int r=0;r<16;++r) {
      float v = e[r];
      v += __shfl_xor(v,1); v += __shfl_xor(v,2); v += __shfl_xor(v,4);
      v += __shfl_xor(v,8); v += __shfl_xor(v,16);
      if ((lane & 31) == 0) atomicAdd(&sumS[(r&3)+8*(r>>2)+4*half], v);
    }
  }
  __syncthreads();
  if (tid < NG) {
    float v = sumS[tid];
    if (v != 0.f) atomicAdd(&lineSum[tid], v);
  }
}

__global__ void epilogue_kernel(const float* __restrict__ sumG, const float* __restrict__ alnG,
                                const float* __restrict__ sw, float* __restrict__ out) {
  constexpr int N3 = 54000, N5 = 11664, N9 = 2000;
  constexpr int TOT = N3 + N5 + N9;
  __shared__ float wred[4];
  int idx = blockIdx.x*256 + threadIdx.x;
  float w0 = sw[0], w1 = sw[1], w2 = sw[2];
  float mx = fmaxf(w0, fmaxf(w1, w2));
  float e0 = __expf(w0-mx), e1 = __expf(w1-mx), e2 = __expf(w2-mx);
  float ise = 1.0f/(e0+e1+e2);
  float c = 0.f;
  if (idx < TOT) {
    float coef;
    if (idx < N3)            coef = e0*ise/(float)N3;
    else if (idx < N3+N5)    coef = e1*ise/(float)N5;
    else                     coef = e2*ise/(float)N9;
    c = (__logf(sumG[idx]) - alnG[idx]) * coef;
  }
  #pragma unroll
  for (int o=32;o;o>>=1) c += __shfl_xor(c, o);
  if ((threadIdx.x & 63)==0) wred[threadIdx.x>>6] = c;
  __syncthreads();
  if (threadIdx.x==0) {
    float s = wred[0]+wred[1]+wred[2]+wred[3];
    if (s != 0.f) atomicAdd(out, s);
  }
}

static inline int cdiv(long long a, int b) { return (int)((a + b - 1) / b); }

template<int P, int R, int KB, int KSPLIT, int CPW, int NCHMAX>
static void run_scale(const float* Yf, const float* Ym, ushort* pkF, ushort* pkM,
                      float* sumG, float* alnG, hipStream_t s) {
  constexpr int NG=90/P, N=NG*NG*NG;
  pack_kernel<P><<<2*N, 64, 0, s>>>(Yf, pkF);
  pack_kernel<P><<<2*N, 64, 0, s>>>(Ym, pkM);
  loss_kernel<P,R,KB,KSPLIT,CPW,NCHMAX><<<2*NG*NG*(2*R+1), 256, 0, s>>>(pkF, pkM, sumG, alnG);
}

extern "C" void kernel_launch(void* const* d_in, const int* in_sizes, int n_in,
                              void* d_out, int out_size, void* d_ws, size_t ws_size,
                              hipStream_t stream) {
  const float* fixedI  = (const float*)d_in[0];
  const float* movingI = (const float*)d_in[1];
  const float* scale_w = (const float*)d_in[2];
  float* out = (float*)d_out;

  uint8_t* w = (uint8_t*)d_ws;
  float*  smallb = (float*)w;                    // [0]=mv_f [1]=mv_m
  float*  sumG = (float*)(w + 4096);
  float*  alnG = sumG + 67664;
  ushort* PK  = (ushort*)(w + (1u<<20));
  float*  X   = (float*)(w + (1u<<20));          // alias of PK
  float*  Yf  = (float*)(w + (1u<<20) + 69984000);
  float*  Ym  = Yf + 17496000;
  ushort* pkF = PK;
  ushort* pkM = PK + 17496000;

  hipMemsetAsync(w, 0, 4096 + 67664*4, stream);  // smallb + sumG (alnG always overwritten)
  hipMemsetAsync(d_out, 0, sizeof(float), stream);

  const int gE = cdiv(17496000, 256);
  const int gV = cdiv(1458000, 256);

  diff2z_kernel<<<gE,256,0,stream>>>(fixedI, X);
  boxy_kernel<<<gE,256,0,stream>>>(X, Yf);
  boxxmin_kernel<<<gV,256,0,stream>>>(Yf, X, smallb+0);
  finalize_kernel<<<gV,256,0,stream>>>(X, Yf, smallb+0);

  diff2z_kernel<<<gE,256,0,stream>>>(movingI, X);
  boxy_kernel<<<gE,256,0,stream>>>(X, Ym);
  boxxmin_kernel<<<gV,256,0,stream>>>(Ym, X, smallb+1);
  finalize_kernel<<<gV,256,0,stream>>>(X, Ym, smallb+1);

  // P3: KB=3, no K-split, chunks {wv, wv+4}; P5: KB=4, K-split 2; P9: KB=8, K-split 4
  run_scale<3,3,3,1,2,7>(Yf, Ym, pkF, pkM, sumG,         alnG,         stream);
  run_scale<5,2,4,2,2,3>(Yf, Ym, pkF, pkM, sumG + 54000, alnG + 54000, stream);
  run_scale<9,1,8,4,1,1>(Yf, Ym, pkF, pkM, sumG + 65664, alnG + 65664, stream);

  epilogue_kernel<<<cdiv(67664,256),256,0,stream>>>(sumG, alnG, scale_w, out);
}

// Round 8
// 1195.103 us; speedup vs baseline: 1.6062x; 1.6062x over previous
//
#include <hip/hip_runtime.h>
#include <hip/hip_bf16.h>
#include <math.h>

#define VOL 729000
#define SL  8100
#define RW  90

typedef __attribute__((ext_vector_type(8))) short s8v;
typedef __attribute__((ext_vector_type(4))) float f32x4;

__device__ __constant__ int c_o1[12][3] = {
  {0,0,-2},{0,-2,0},{0,-2,0},{0,0,2},{0,0,2},{2,0,0},{2,0,0},{2,0,0},{0,2,0},{0,2,0},{0,2,0},{0,2,0}
};
__device__ __constant__ int c_o2[12][3] = {
  {-2,0,0},{-2,0,0},{0,0,-2},{-2,0,0},{0,-2,0},{0,0,-2},{0,-2,0},{0,0,2},{-2,0,0},{0,0,-2},{0,0,2},{2,0,0}
};

__device__ __forceinline__ int clampi(int v, int lo, int hi){ return v<lo?lo:(v>hi?hi:v); }

typedef __attribute__((address_space(3))) uint lds_uint;
typedef __attribute__((address_space(1))) uint glb_uint;
__device__ __forceinline__ void gl_lds16(const ushort* g, ushort* l) {
  __builtin_amdgcn_global_load_lds((const glb_uint*)g, (lds_uint*)l, 16, 0, 0);
}
__device__ __forceinline__ float bf2f(uint u) { return __uint_as_float(u << 16); }

__global__ void diff2z_kernel(const float* __restrict__ img, float* __restrict__ out) {
  int idx = blockIdx.x*256 + threadIdx.x;
  if (idx >= 2*12*VOL) return;
  int vox = idx % VOL; int ct = idx / VOL; int t = ct % 12, b = ct / 12;
  int z = vox / SL; int r = vox % SL; int y = r / RW; int x = r % RW;
  const float* im = img + (size_t)b*VOL;
  int o1z=c_o1[t][0], o1y=c_o1[t][1], o1x=c_o1[t][2];
  int o2z=c_o2[t][0], o2y=c_o2[t][1], o2x=c_o2[t][2];
  int y1 = clampi(y+o1y,0,89), x1 = clampi(x+o1x,0,89);
  int y2 = clampi(y+o2y,0,89), x2 = clampi(x+o2x,0,89);
  float s = 0.f;
  #pragma unroll
  for (int d=-2; d<=2; ++d) {
    int zz = clampi(z+d,0,89);
    int z1 = clampi(zz+o1z,0,89), z2 = clampi(zz+o2z,0,89);
    float dv = im[z1*SL+y1*RW+x1] - im[z2*SL+y2*RW+x2];
    s += dv*dv;
  }
  out[idx] = s;
}

__global__ void boxy_kernel(const float* __restrict__ in, float* __restrict__ out) {
  int idx = blockIdx.x*256 + threadIdx.x;
  if (idx >= 2*12*VOL) return;
  int vox = idx % VOL; int bc = idx / VOL;
  int z = vox / SL; int r = vox % SL; int y = r / RW; int x = r % RW;
  const float* p = in + (size_t)bc*VOL + (size_t)z*SL + x;
  float s = 0.f;
  #pragma unroll
  for (int d=-2; d<=2; ++d) { int yc = clampi(y+d,0,89); s += p[yc*RW]; }
  out[idx] = s;
}

__global__ void boxxmin_kernel(const float* __restrict__ in, float* __restrict__ outPre,
                               float* __restrict__ mvsum) {
  __shared__ float red;
  if (threadIdx.x == 0) red = 0.f;
  __syncthreads();
  int idx = blockIdx.x*256 + threadIdx.x;
  float mv = 0.f;
  if (idx < 2*VOL) {
    int b = idx / VOL; int vox = idx % VOL;
    int z = vox / SL; int r = vox % SL; int y = r / RW; int x = r % RW;
    const float* base = in + (size_t)b*12*VOL + (size_t)z*SL + (size_t)y*RW;
    float s[12]; float mn = 3.4e38f;
    #pragma unroll
    for (int c=0;c<12;++c) {
      const float* pc = base + (size_t)c*VOL;
      float t = 0.f;
      #pragma unroll
      for (int d=-2;d<=2;++d) { int xc = clampi(x+d,0,89); t += pc[xc]; }
      t *= (1.0f/125.0f);
      s[c] = t; mn = fminf(mn, t);
    }
    float* ob = outPre + (size_t)b*12*VOL + vox;
    #pragma unroll
    for (int c=0;c<12;++c) { float pre = s[c]-mn; ob[(size_t)c*VOL] = pre; mv += pre; }
    mv *= (1.0f/12.0f);
  }
  #pragma unroll
  for (int o=32;o;o>>=1) mv += __shfl_xor(mv, o);
  if ((threadIdx.x & 63)==0 && mv != 0.f) atomicAdd(&red, mv);
  __syncthreads();
  if (threadIdx.x==0) atomicAdd(mvsum, red);
}

// pre -> bf16 mind volume: exp(-pre / clip(mean_c(pre), mm*1e-3, mm*1e3))
__global__ void finalize_kernel(const float* __restrict__ pre, ushort* __restrict__ out,
                                const float* __restrict__ mvsum) {
  int idx = blockIdx.x*256 + threadIdx.x;
  if (idx >= 2*VOL) return;
  int b = idx / VOL; int vox = idx % VOL;
  const float* base = pre + (size_t)b*12*VOL + vox;
  ushort* ob = out + (size_t)b*12*VOL + vox;
  float s[12]; float mv = 0.f;
  #pragma unroll
  for (int c=0;c<12;++c) { s[c] = base[(size_t)c*VOL]; mv += s[c]; }
  mv *= (1.0f/12.0f);
  float mm = *mvsum * (1.0f/1458000.0f);
  float mvc = fminf(fmaxf(mv, mm*0.001f), mm*1000.0f);
  float inv = 1.0f / mvc;
  #pragma unroll
  for (int c=0;c<12;++c) {
    __hip_bfloat16 h = __float2bfloat16(__expf(-s[c]*inv));
    ob[(size_t)c*VOL] = *(ushort*)&h;
  }
}

// LDS-transpose pack: block = (b,gz,gy) line. Coalesced slab read (CCH channels
// at a time), coalesced packed write [d][k], raw bf16 (norms separate).
template<int P, int CCH>
__global__ __launch_bounds__(256) void packn_kernel(const ushort* __restrict__ Ybf,
                                                    ushort* __restrict__ pk) {
  constexpr int NG=90/P, N=NG*NG*NG, C=12*P*P*P;
  constexpr int P2=P*P, P3=P*P*P;
  constexpr int ROWS = CCH*P2;
  constexpr int HALF = CCH*P3/2;
  __shared__ uint slabU[ROWS*48];             // rows of 90 ushorts padded to 96
  int blk = blockIdx.x;
  int gy = blk % NG; int t1 = blk / NG; int gz = t1 % NG; int b = t1 / NG;
  int tid = threadIdx.x;
  size_t obase = ((size_t)b*N + ((size_t)gz*NG + gy)*NG) * C;
  for (int c0 = 0; c0 < 12; c0 += CCH) {
    if (c0) __syncthreads();
    for (int i = tid; i < ROWS*45; i += 256) {
      int r = i/45, xu = i - r*45;
      int c = c0 + r/P2; int rr = r % P2; int dz = rr/P, dy = rr - dz*P;
      const ushort* src = Ybf + ((size_t)(b*12 + c)*VOL + (size_t)(gz*P+dz)*SL + (size_t)(gy*P+dy)*RW);
      slabU[r*48 + xu] = *(const uint*)(src + 2*xu);
    }
    __syncthreads();
    const ushort* slab = (const ushort*)slabU;
    for (int i = tid; i < NG*HALF; i += 256) {
      int d = i/HALF, j2 = i - d*HALF;
      int k = 2*j2;
      int cc = k/P3; int rem = k - cc*P3;
      int dz = rem/P2; int r2 = rem - dz*P2; int dy = r2/P; int dx = r2 - dy*P;
      uint lo = slab[((cc*P + dz)*P + dy)*96 + d*P + dx];
      int k1 = k+1;
      int cc1 = k1/P3; int rem1 = k1 - cc1*P3;
      int dz1 = rem1/P2; int r21 = rem1 - dz1*P2; int dy1 = r21/P; int dx1 = r21 - dy1*P;
      uint hi = slab[((cc1*P + dz1)*P + dy1)*96 + d*P + dx1];
      *(uint*)(pk + obase + (size_t)d*C + c0*P3 + k) = lo | (hi << 16);
    }
  }
}

// inverse L2 norm of each packed descriptor
template<int C>
__global__ __launch_bounds__(64) void normk(const ushort* __restrict__ pk,
                                            float* __restrict__ inv) {
  int d = blockIdx.x; int lane = threadIdx.x;
  const uint* p = (const uint*)(pk + (size_t)d*C);
  float ss = 0.f;
  for (int i = lane; i < C/2; i += 64) {
    uint u = p[i];
    float a = bf2f(u & 0xffffu), bb = bf2f(u >> 16);
    ss += a*a + bb*bb;
  }
  #pragma unroll
  for (int o=32;o;o>>=1) ss += __shfl_xor(ss, o);
  if (lane==0) inv[d] = 1.0f / fmaxf(sqrtf(ss), 1e-12f);
}

union FragU { s8v s; uint u[4]; };
__device__ __forceinline__ s8v ldfrag_m(const ushort* p, bool v0, bool v1) {
  FragU f;
  if (v0) { uint2 a = *(const uint2*)p;     f.u[0]=a.x; f.u[1]=a.y; } else { f.u[0]=0; f.u[1]=0; }
  if (v1) { uint2 b = *(const uint2*)(p+4); f.u[2]=b.x; f.u[3]=b.y; } else { f.u[2]=0; f.u[3]=0; }
  return f.s;
}

// R6 loss structure (16x16x32, frag-native LDS staging) + raw descriptors:
// sim = raw_dot * invA[x] * invB[m] applied in the round epilogue.
template<int P, int R, int NRT, int TPB, bool AFULL>
__global__ __launch_bounds__(TPB) void loss_kernel(
    const ushort* __restrict__ pkF, const ushort* __restrict__ pkM,
    const float* __restrict__ invF, const float* __restrict__ invM,
    float* __restrict__ sumG, float* __restrict__ alnG) {
  constexpr int NG=90/P, N=NG*NG*NG, C=12*P*P*P;
  constexpr int NW=TPB/64, WZ=2*R+1;
  constexpr int KMAIN = C & ~31;
  constexpr int NKB = (KMAIN + 127)/128;
  constexpr int NROWS = NRT*16;
  constexpr int ATILES = AFULL ? 0 : 4*NRT;
  constexpr int PHTILES = ATILES + NW*4;
  constexpr int AFT = AFULL ? (KMAIN/32)*NRT : 1;
  static_assert(NROWS >= NG, "rows cover x line");
  __shared__ float sumS[NROWS];
  __shared__ float invAS[NROWS];
  __shared__ __align__(16) ushort aT[AFT*512];
  __shared__ __align__(16) ushort bP[2][PHTILES*512];

  int nwg = gridDim.x;
  int q = nwg >> 3, r8 = nwg & 7;
  int xcd = blockIdx.x & 7, sidx = blockIdx.x >> 3;
  int lid = (xcd < r8 ? xcd*(q+1) : r8*(q+1) + (xcd - r8)*q) + sidx;
  int j = lid % WZ; int t1 = lid / WZ;
  int gy = t1 % NG; t1 /= NG;
  int mz = t1 % NG; int b = t1 / NG;
  int gz = mz - R + j;
  if (gz < 0 || gz >= NG) return;
  int tid = threadIdx.x; int lane = tid & 63; int wv = tid >> 6;
  int col = lane & 15, grp = lane >> 4;
  const int ko = grp*8;
  for (int i = tid; i < NROWS; i += TPB) {
    sumS[i] = 0.f;
    invAS[i] = (i < NG) ? invF[(size_t)b*N + ((size_t)gz*NG + gy)*NG + i] : 0.f;
  }

  size_t baseF = ((size_t)b*N + ((size_t)gz*NG + gy)*NG) * C;
  const ushort* aRow[NRT];
  #pragma unroll
  for (int t=0;t<NRT;++t) {
    int row = t*16 + col; if (row > NG-1) row = NG-1;
    aRow[t] = pkF + baseF + (size_t)row*C;
  }
  int y0 = max(gy-R,0), y1 = min(gy+R,NG-1);
  int wy = y1-y0+1;
  int Ms = wy*NG;
  int nch = (Ms+15)>>4;
  const ushort* sliceM = pkM + ((size_t)b*N + ((size_t)mz*NG + y0)*NG) * C;
  const float* invMsl  = invM + (size_t)b*N + ((size_t)mz*NG + y0)*NG;
  float* lineSum = sumG + (size_t)b*N + ((size_t)gz*NG + gy)*NG;
  float* lineAln = alnG + (size_t)b*N + ((size_t)gz*NG + gy)*NG;

  int NR = (nch + NW - 1)/NW;
  int NP = NR*NKB;

  auto stageA = [&](int kb, ushort* dst) {
    int k4cnt = min(4, (KMAIN - kb*128) >> 5);
    for (int i = wv; i < 4*NRT; i += NW) {
      int k4 = i/NRT, t = i - k4*NRT;
      if (k4 < k4cnt)
        gl_lds16(aRow[t] + kb*128 + k4*32 + ko, dst + i*512);
    }
  };
  auto stageB = [&](int r, int kb, ushort* dstB) {
    int k4cnt = min(4, (KMAIN - kb*128) >> 5);
    int chunk = r*NW + wv;
    if (chunk < nch) {
      int descIdx = chunk*16 + col;
      int desc = min(descIdx, Ms-1);
      const ushort* srcD = sliceM + (size_t)desc*C + kb*128 + ko;
      for (int k4 = 0; k4 < k4cnt; ++k4)
        gl_lds16(srcD + k4*32, dstB + (wv*4 + k4)*512);
    }
  };

  if constexpr (AFULL) {
    for (int i = wv; i < (KMAIN/32)*NRT; i += NW) {
      int ak4 = i/NRT, t = i - ak4*NRT;
      gl_lds16(aRow[t] + ak4*32 + ko, aT + i*512);
    }
  } else {
    stageA(0, bP[0]);
  }
  stageB(0, 0, bP[0] + ATILES*512);
  __syncthreads();

  float sumE[NRT][4];
  f32x4 acc[NRT];
  #pragma unroll
  for (int t=0;t<NRT;++t) {
    acc[t] = (f32x4){0.f,0.f,0.f,0.f};
    #pragma unroll
    for (int jj=0;jj<4;++jj) sumE[t][jj] = 0.f;
  }

  int buf = 0;
  for (int p = 0; p < NP; ++p) {
    int r = p/NKB, kb = p - r*NKB;
    int pn = p + 1;
    if (pn < NP) {
      int rn = pn/NKB, kbn = pn - rn*NKB;
      if constexpr (!AFULL) stageA(kbn, bP[buf^1]);
      stageB(rn, kbn, bP[buf^1] + ATILES*512);
    }
    int k4cnt = min(4, (KMAIN - kb*128) >> 5);
    int chunk = r*NW + wv;
    if (chunk < nch) {
      const ushort* bbase = bP[buf] + (ATILES + wv*4)*512 + lane*8;
      for (int k4 = 0; k4 < k4cnt; ++k4) {
        s8v bf = *(const s8v*)(bbase + k4*512);
        #pragma unroll
        for (int t=0;t<NRT;++t) {
          const ushort* ap;
          if constexpr (AFULL) ap = aT + (((kb*4 + k4)*NRT) + t)*512 + lane*8;
          else                 ap = bP[buf] + (k4*NRT + t)*512 + lane*8;
          s8v af = *(const s8v*)ap;
          acc[t] = __builtin_amdgcn_mfma_f32_16x16x32_bf16(af, bf, acc[t], 0,0,0);
        }
      }
      if (kb == NKB-1) {
        int mu = chunk*16 + col; bool vm = mu < Ms;
        int mus = vm ? mu : 0;
        const ushort* pb = sliceM + (size_t)mus*C;
        int kg = KMAIN + ko;
        bool v0 = (kg+4 <= C), v1 = (kg+8 <= C);
        if constexpr ((C & 31) != 0) {
          s8v bft = ldfrag_m(pb + kg, v0, v1);
          #pragma unroll
          for (int t=0;t<NRT;++t) {
            s8v aft = ldfrag_m(aRow[t] + kg, v0, v1);
            acc[t] = __builtin_amdgcn_mfma_f32_16x16x32_bf16(aft, bft, acc[t], 0,0,0);
          }
        }
        float invBm = invMsl[mus];
        int myq = mus/NG; int my = y0 + myq; int mx = mus - myq*NG;
        #pragma unroll
        for (int t=0;t<NRT;++t) {
          #pragma unroll
          for (int jj=0;jj<4;++jj) {
            int x = t*16 + grp*4 + jj;
            float sim = acc[t][jj] * invAS[x < NROWS ? x : 0] * invBm;
            bool ok = vm && (x < NG) && (mx - x <= R) && (x - mx <= R);
            if (ok) {
              sumE[t][jj] += __expf(sim);
              if (mz==gz && my==gy && mx==x) lineAln[x] = sim;
            }
          }
          acc[t] = (f32x4){0.f,0.f,0.f,0.f};
        }
      }
    }
    __syncthreads();
    buf ^= 1;
  }

  #pragma unroll
  for (int t=0;t<NRT;++t) {
    #pragma unroll
    for (int jj=0;jj<4;++jj) {
      float v = sumE[t][jj];
      v += __shfl_xor(v,1); v += __shfl_xor(v,2); v += __shfl_xor(v,4); v += __shfl_xor(v,8);
      if (col==0) atomicAdd(&sumS[t*16 + grp*4 + jj], v);
    }
  }
  __syncthreads();
  if (tid < NG) {
    float v = sumS[tid];
    if (v != 0.f) atomicAdd(&lineSum[tid], v);
  }
}

__global__ void epilogue_kernel(const float* __restrict__ sumG, const float* __restrict__ alnG,
                                const float* __restrict__ sw, float* __restrict__ out) {
  constexpr int N3 = 54000, N5 = 11664, N9 = 2000;
  constexpr int TOT = N3 + N5 + N9;
  __shared__ float wred[4];
  int idx = blockIdx.x*256 + threadIdx.x;
  float w0 = sw[0], w1 = sw[1], w2 = sw[2];
  float mx = fmaxf(w0, fmaxf(w1, w2));
  float e0 = __expf(w0-mx), e1 = __expf(w1-mx), e2 = __expf(w2-mx);
  float ise = 1.0f/(e0+e1+e2);
  float c = 0.f;
  if (idx < TOT) {
    float coef;
    if (idx < N3)            coef = e0*ise/(float)N3;
    else if (idx < N3+N5)    coef = e1*ise/(float)N5;
    else                     coef = e2*ise/(float)N9;
    c = (__logf(sumG[idx]) - alnG[idx]) * coef;
  }
  #pragma unroll
  for (int o=32;o;o>>=1) c += __shfl_xor(c, o);
  if ((threadIdx.x & 63)==0) wred[threadIdx.x>>6] = c;
  __syncthreads();
  if (threadIdx.x==0) {
    float s = wred[0]+wred[1]+wred[2]+wred[3];
    if (s != 0.f) atomicAdd(out, s);
  }
}

static inline int cdiv(long long a, int b) { return (int)((a + b - 1) / b); }

template<int P, int R, int NRT, int TPB, bool AFULL, int CCH>
static void run_scale(const ushort* Yf, const ushort* Ym, ushort* pkF, ushort* pkM,
                      float* invPF, float* invPM, float* sumG, float* alnG, hipStream_t s) {
  constexpr int NG=90/P, N=NG*NG*NG, C=12*P*P*P;
  packn_kernel<P,CCH><<<2*NG*NG, 256, 0, s>>>(Yf, pkF);
  packn_kernel<P,CCH><<<2*NG*NG, 256, 0, s>>>(Ym, pkM);
  normk<C><<<2*N, 64, 0, s>>>(pkF, invPF);
  normk<C><<<2*N, 64, 0, s>>>(pkM, invPM);
  loss_kernel<P,R,NRT,TPB,AFULL><<<2*NG*NG*(2*R+1), TPB, 0, s>>>(pkF, pkM, invPF, invPM, sumG, alnG);
}

extern "C" void kernel_launch(void* const* d_in, const int* in_sizes, int n_in,
                              void* d_out, int out_size, void* d_ws, size_t ws_size,
                              hipStream_t stream) {
  const float* fixedI  = (const float*)d_in[0];
  const float* movingI = (const float*)d_in[1];
  const float* scale_w = (const float*)d_in[2];
  float* out = (float*)d_out;

  uint8_t* w = (uint8_t*)d_ws;
  float*  smallb = (float*)w;                    // [0]=mv_f [1]=mv_m
  float*  sumG  = (float*)(w + 4096);
  float*  alnG  = sumG + 67664;
  float*  invPF = alnG + 67664;
  float*  invPM = invPF + 67664;
  uint8_t* big = w + (2u<<20);
  float*  A   = (float*)big;                      // 70MB f32 scratch
  float*  Bf  = (float*)(big + 69984000);         // 70MB f32 scratch / PK region
  ushort* pkF = (ushort*)Bf;
  ushort* pkM = pkF + 17496000;
  ushort* Ybf_f = (ushort*)(big + 2*69984000ull);
  ushort* Ybf_m = Ybf_f + 17496000;

  hipMemsetAsync(w, 0, 4096 + 67664*4, stream);   // smallb + sumG
  hipMemsetAsync(d_out, 0, sizeof(float), stream);

  const int gE = cdiv(17496000, 256);
  const int gV = cdiv(1458000, 256);

  // MIND(fixed): diff2z->Bf, boxy->A, boxxmin->Bf(pre), finalize->Ybf_f
  diff2z_kernel<<<gE,256,0,stream>>>(fixedI, Bf);
  boxy_kernel<<<gE,256,0,stream>>>(Bf, A);
  boxxmin_kernel<<<gV,256,0,stream>>>(A, Bf, smallb+0);
  finalize_kernel<<<gV,256,0,stream>>>(Bf, Ybf_f, smallb+0);

  // MIND(moving): diff2z->A, boxy->Bf, boxxmin->A(pre), finalize->Ybf_m
  diff2z_kernel<<<gE,256,0,stream>>>(movingI, A);
  boxy_kernel<<<gE,256,0,stream>>>(A, Bf);
  boxxmin_kernel<<<gV,256,0,stream>>>(Bf, A, smallb+1);
  finalize_kernel<<<gV,256,0,stream>>>(A, Ybf_m, smallb+1);

  run_scale<3,3,2,256,true ,12>(Ybf_f, Ybf_m, pkF, pkM, invPF,         invPM,         sumG,         alnG,         stream);
  run_scale<5,2,2,256,false, 6>(Ybf_f, Ybf_m, pkF, pkM, invPF + 54000, invPM + 54000, sumG + 54000, alnG + 54000, stream);
  run_scale<9,1,1,128,false, 2>(Ybf_f, Ybf_m, pkF, pkM, invPF + 65664, invPM + 65664, sumG + 65664, alnG + 65664, stream);

  epilogue_kernel<<<cdiv(67664,256),256,0,stream>>>(sumG, alnG, scale_w, out);
}

// Round 9
// 1158.361 us; speedup vs baseline: 1.6571x; 1.0317x over previous
//
#include <hip/hip_runtime.h>
#include <hip/hip_bf16.h>
#include <math.h>

#define VOL 729000
#define SL  8100
#define RW  90

typedef __attribute__((ext_vector_type(8))) short s8v;
typedef __attribute__((ext_vector_type(4))) float f32x4;

__device__ __constant__ int c_o1[12][3] = {
  {0,0,-2},{0,-2,0},{0,-2,0},{0,0,2},{0,0,2},{2,0,0},{2,0,0},{2,0,0},{0,2,0},{0,2,0},{0,2,0},{0,2,0}
};
__device__ __constant__ int c_o2[12][3] = {
  {-2,0,0},{-2,0,0},{0,0,-2},{-2,0,0},{0,-2,0},{0,0,-2},{0,-2,0},{0,0,2},{-2,0,0},{0,0,-2},{0,0,2},{2,0,0}
};

__device__ __forceinline__ int clampi(int v, int lo, int hi){ return v<lo?lo:(v>hi?hi:v); }

typedef __attribute__((address_space(3))) uint lds_uint;
typedef __attribute__((address_space(1))) uint glb_uint;
__device__ __forceinline__ void gl_lds16(const ushort* g, ushort* l) {
  __builtin_amdgcn_global_load_lds((const glb_uint*)g, (lds_uint*)l, 16, 0, 0);
}
__device__ __forceinline__ float bf2f(uint u) { return __uint_as_float(u << 16); }

__global__ void diff2z_kernel(const float* __restrict__ img, float* __restrict__ out) {
  int idx = blockIdx.x*256 + threadIdx.x;
  if (idx >= 2*12*VOL) return;
  int vox = idx % VOL; int ct = idx / VOL; int t = ct % 12, b = ct / 12;
  int z = vox / SL; int r = vox % SL; int y = r / RW; int x = r % RW;
  const float* im = img + (size_t)b*VOL;
  int o1z=c_o1[t][0], o1y=c_o1[t][1], o1x=c_o1[t][2];
  int o2z=c_o2[t][0], o2y=c_o2[t][1], o2x=c_o2[t][2];
  int y1 = clampi(y+o1y,0,89), x1 = clampi(x+o1x,0,89);
  int y2 = clampi(y+o2y,0,89), x2 = clampi(x+o2x,0,89);
  float s = 0.f;
  #pragma unroll
  for (int d=-2; d<=2; ++d) {
    int zz = clampi(z+d,0,89);
    int z1 = clampi(zz+o1z,0,89), z2 = clampi(zz+o2z,0,89);
    float dv = im[z1*SL+y1*RW+x1] - im[z2*SL+y2*RW+x2];
    s += dv*dv;
  }
  out[idx] = s;
}

__global__ void boxy_kernel(const float* __restrict__ in, float* __restrict__ out) {
  int idx = blockIdx.x*256 + threadIdx.x;
  if (idx >= 2*12*VOL) return;
  int vox = idx % VOL; int bc = idx / VOL;
  int z = vox / SL; int r = vox % SL; int y = r / RW; int x = r % RW;
  const float* p = in + (size_t)bc*VOL + (size_t)z*SL + x;
  float s = 0.f;
  #pragma unroll
  for (int d=-2; d<=2; ++d) { int yc = clampi(y+d,0,89); s += p[yc*RW]; }
  out[idx] = s;
}

__global__ void boxxmin_kernel(const float* __restrict__ in, float* __restrict__ outPre,
                               float* __restrict__ mvsum) {
  __shared__ float red;
  if (threadIdx.x == 0) red = 0.f;
  __syncthreads();
  int idx = blockIdx.x*256 + threadIdx.x;
  float mv = 0.f;
  if (idx < 2*VOL) {
    int b = idx / VOL; int vox = idx % VOL;
    int z = vox / SL; int r = vox % SL; int y = r / RW; int x = r % RW;
    const float* base = in + (size_t)b*12*VOL + (size_t)z*SL + (size_t)y*RW;
    float s[12]; float mn = 3.4e38f;
    #pragma unroll
    for (int c=0;c<12;++c) {
      const float* pc = base + (size_t)c*VOL;
      float t = 0.f;
      #pragma unroll
      for (int d=-2;d<=2;++d) { int xc = clampi(x+d,0,89); t += pc[xc]; }
      t *= (1.0f/125.0f);
      s[c] = t; mn = fminf(mn, t);
    }
    float* ob = outPre + (size_t)b*12*VOL + vox;
    #pragma unroll
    for (int c=0;c<12;++c) { float pre = s[c]-mn; ob[(size_t)c*VOL] = pre; mv += pre; }
    mv *= (1.0f/12.0f);
  }
  #pragma unroll
  for (int o=32;o;o>>=1) mv += __shfl_xor(mv, o);
  if ((threadIdx.x & 63)==0 && mv != 0.f) atomicAdd(&red, mv);
  __syncthreads();
  if (threadIdx.x==0) atomicAdd(mvsum, red);
}

__global__ void finalize_kernel(const float* __restrict__ pre, ushort* __restrict__ out,
                                const float* __restrict__ mvsum) {
  int idx = blockIdx.x*256 + threadIdx.x;
  if (idx >= 2*VOL) return;
  int b = idx / VOL; int vox = idx % VOL;
  const float* base = pre + (size_t)b*12*VOL + vox;
  ushort* ob = out + (size_t)b*12*VOL + vox;
  float s[12]; float mv = 0.f;
  #pragma unroll
  for (int c=0;c<12;++c) { s[c] = base[(size_t)c*VOL]; mv += s[c]; }
  mv *= (1.0f/12.0f);
  float mm = *mvsum * (1.0f/1458000.0f);
  float mvc = fminf(fmaxf(mv, mm*0.001f), mm*1000.0f);
  float inv = 1.0f / mvc;
  #pragma unroll
  for (int c=0;c<12;++c) {
    __hip_bfloat16 h = __float2bfloat16(__expf(-s[c]*inv));
    ob[(size_t)c*VOL] = *(ushort*)&h;
  }
}

// LDS-transpose pack: block = (b,gz,gy) line. Coalesced slab read, coalesced
// packed write [d][k], raw bf16 (norms separate).
template<int P, int CCH>
__global__ __launch_bounds__(256) void packn_kernel(const ushort* __restrict__ Ybf,
                                                    ushort* __restrict__ pk) {
  constexpr int NG=90/P, N=NG*NG*NG, C=12*P*P*P;
  constexpr int P2=P*P, P3=P*P*P;
  constexpr int ROWS = CCH*P2;
  constexpr int HALF = CCH*P3/2;
  __shared__ uint slabU[ROWS*48];
  int blk = blockIdx.x;
  int gy = blk % NG; int t1 = blk / NG; int gz = t1 % NG; int b = t1 / NG;
  int tid = threadIdx.x;
  size_t obase = ((size_t)b*N + ((size_t)gz*NG + gy)*NG) * C;
  for (int c0 = 0; c0 < 12; c0 += CCH) {
    if (c0) __syncthreads();
    for (int i = tid; i < ROWS*45; i += 256) {
      int r = i/45, xu = i - r*45;
      int c = c0 + r/P2; int rr = r % P2; int dz = rr/P, dy = rr - dz*P;
      const ushort* src = Ybf + ((size_t)(b*12 + c)*VOL + (size_t)(gz*P+dz)*SL + (size_t)(gy*P+dy)*RW);
      slabU[r*48 + xu] = *(const uint*)(src + 2*xu);
    }
    __syncthreads();
    const ushort* slab = (const ushort*)slabU;
    for (int i = tid; i < NG*HALF; i += 256) {
      int d = i/HALF, j2 = i - d*HALF;
      int k = 2*j2;
      int cc = k/P3; int rem = k - cc*P3;
      int dz = rem/P2; int r2 = rem - dz*P2; int dy = r2/P; int dx = r2 - dy*P;
      uint lo = slab[((cc*P + dz)*P + dy)*96 + d*P + dx];
      int k1 = k+1;
      int cc1 = k1/P3; int rem1 = k1 - cc1*P3;
      int dz1 = rem1/P2; int r21 = rem1 - dz1*P2; int dy1 = r21/P; int dx1 = r21 - dy1*P;
      uint hi = slab[((cc1*P + dz1)*P + dy1)*96 + d*P + dx1];
      *(uint*)(pk + obase + (size_t)d*C + c0*P3 + k) = lo | (hi << 16);
    }
  }
}

template<int C>
__global__ __launch_bounds__(64) void normk(const ushort* __restrict__ pk,
                                            float* __restrict__ inv) {
  int d = blockIdx.x; int lane = threadIdx.x;
  const uint* p = (const uint*)(pk + (size_t)d*C);
  float ss = 0.f;
  for (int i = lane; i < C/2; i += 64) {
    uint u = p[i];
    float a = bf2f(u & 0xffffu), bb = bf2f(u >> 16);
    ss += a*a + bb*bb;
  }
  #pragma unroll
  for (int o=32;o;o>>=1) ss += __shfl_xor(ss, o);
  if (lane==0) inv[d] = 1.0f / fmaxf(sqrtf(ss), 1e-12f);
}

union FragU { s8v s; uint u[4]; };
__device__ __forceinline__ s8v ldfrag_m(const ushort* p, bool v0, bool v1) {
  FragU f;
  if (v0) { uint2 a = *(const uint2*)p;     f.u[0]=a.x; f.u[1]=a.y; } else { f.u[0]=0; f.u[1]=0; }
  if (v1) { uint2 b = *(const uint2*)(p+4); f.u[2]=b.x; f.u[3]=b.y; } else { f.u[2]=0; f.u[3]=0; }
  return f.s;
}

// Chunk-persistent loss: block = (b, mz, gy, j), gz = mz-R+j (plane-major +
// bijective XCD swizzle). Phases iterate K only (KB 32-elem k-steps, dbuf);
// per k-step a wave loads its A-frags ONCE into registers and reuses them
// across all its chunks (acc[ci][t] persistent across the whole K loop).
// LDS tile layout == MFMA fragment order -> all reads linear ds_read_b128.
template<int P, int R, int NRT, int TPB, int KB, int NCHMAX, int CPW, bool AFULL>
__global__ __launch_bounds__(TPB) void loss_kernel(
    const ushort* __restrict__ pkF, const ushort* __restrict__ pkM,
    const float* __restrict__ invF, const float* __restrict__ invM,
    float* __restrict__ sumG, float* __restrict__ alnG) {
  constexpr int NG=90/P, N=NG*NG*NG, C=12*P*P*P;
  constexpr int NW=TPB/64, WZ=2*R+1;
  constexpr int KS4 = (C & ~31)/32;          // 10 / 46 / 273
  constexpr int NPH = (KS4 + KB - 1)/KB;
  constexpr int NROWS = NRT*16;
  constexpr int ASLOT = AFULL ? 0 : NRT;
  constexpr int SLOTS = ASLOT + NCHMAX;
  constexpr int AFT = AFULL ? KS4*NRT : 1;
  static_assert(NROWS >= NG, "rows cover x line");
  static_assert(CPW*NW >= NCHMAX, "chunk coverage");
  __shared__ float sumS[NROWS];
  __shared__ float invAS[NROWS];
  __shared__ __align__(16) ushort aT[AFT*512];
  __shared__ __align__(16) ushort bP[2][SLOTS*KB*512];

  int nwg = gridDim.x;
  int q = nwg >> 3, r8 = nwg & 7;
  int xcd = blockIdx.x & 7, sidx = blockIdx.x >> 3;
  int lid = (xcd < r8 ? xcd*(q+1) : r8*(q+1) + (xcd - r8)*q) + sidx;
  int j = lid % WZ; int t1 = lid / WZ;
  int gy = t1 % NG; t1 /= NG;
  int mz = t1 % NG; int b = t1 / NG;
  int gz = mz - R + j;
  if (gz < 0 || gz >= NG) return;
  int tid = threadIdx.x; int lane = tid & 63; int wv = tid >> 6;
  int col = lane & 15, grp = lane >> 4;
  const int ko = grp*8;
  for (int i = tid; i < NROWS; i += TPB) {
    sumS[i] = 0.f;
    invAS[i] = (i < NG) ? invF[(size_t)b*N + ((size_t)gz*NG + gy)*NG + i] : 0.f;
  }

  size_t baseF = ((size_t)b*N + ((size_t)gz*NG + gy)*NG) * C;
  const ushort* aRow[NRT];
  #pragma unroll
  for (int t=0;t<NRT;++t) {
    int row = t*16 + col; if (row > NG-1) row = NG-1;
    aRow[t] = pkF + baseF + (size_t)row*C;
  }
  int y0 = max(gy-R,0), y1 = min(gy+R,NG-1);
  int wy = y1-y0+1;
  int Ms = wy*NG;
  int nch = (Ms+15)>>4;
  const ushort* sliceM = pkM + ((size_t)b*N + ((size_t)mz*NG + y0)*NG) * C;
  const float* invMsl  = invM + (size_t)b*N + ((size_t)mz*NG + y0)*NG;
  float* lineSum = sumG + (size_t)b*N + ((size_t)gz*NG + gy)*NG;
  float* lineAln = alnG + (size_t)b*N + ((size_t)gz*NG + gy)*NG;

  // stage phase ph into dst: A tiles (if !AFULL) at [t*KB+s], B at [(ASLOT+c)*KB+s]
  auto stage = [&](int ph, ushort* dst) {
    int tb = ph*KB;
    int tot = (nch + ASLOT)*KB;
    for (int i = wv; i < tot; i += NW) {
      int slot = i / KB, s = i - slot*KB;
      int ks = tb + s;
      if (ks >= KS4) continue;
      if (slot < nch) {
        int di = slot*16 + col; if (di > Ms-1) di = Ms-1;
        gl_lds16(sliceM + (size_t)di*C + ks*32 + ko, dst + ((ASLOT + slot)*KB + s)*512);
      } else {
        int t = slot - nch;
        gl_lds16(aRow[t] + ks*32 + ko, dst + (t*KB + s)*512);
      }
    }
  };

  if constexpr (AFULL) {
    for (int i2 = wv; i2 < KS4*NRT; i2 += NW) {
      int ks = i2/NRT, t = i2 - ks*NRT;
      gl_lds16(aRow[t] + ks*32 + ko, aT + i2*512);
    }
  }
  stage(0, bP[0]);
  __syncthreads();

  f32x4 acc[CPW][NRT];
  #pragma unroll
  for (int ci=0;ci<CPW;++ci)
    #pragma unroll
    for (int t=0;t<NRT;++t) acc[ci][t] = (f32x4){0.f,0.f,0.f,0.f};

  for (int ph = 0; ph < NPH; ++ph) {
    if (ph+1 < NPH) stage(ph+1, bP[(ph+1)&1]);
    const ushort* buf = bP[ph&1];
    #pragma unroll
    for (int s = 0; s < KB; ++s) {
      int ks = ph*KB + s;
      if (ks >= KS4) break;
      s8v af[NRT];
      #pragma unroll
      for (int t=0;t<NRT;++t) {
        const ushort* ap;
        if constexpr (AFULL) ap = aT + (size_t)(ks*NRT + t)*512 + lane*8;
        else                 ap = buf + (t*KB + s)*512 + lane*8;
        af[t] = *(const s8v*)ap;
      }
      #pragma unroll
      for (int ci=0; ci<CPW; ++ci) {
        int c = wv + ci*NW;
        if (c < nch) {                                   // wave-uniform
          s8v bf = *(const s8v*)(buf + ((ASLOT + c)*KB + s)*512 + lane*8);
          #pragma unroll
          for (int t=0;t<NRT;++t)
            acc[ci][t] = __builtin_amdgcn_mfma_f32_16x16x32_bf16(af[t], bf, acc[ci][t], 0,0,0);
        }
      }
    }
    __syncthreads();
  }

  float sumE[NRT][4];
  #pragma unroll
  for (int t=0;t<NRT;++t) { sumE[t][0]=0.f; sumE[t][1]=0.f; sumE[t][2]=0.f; sumE[t][3]=0.f; }

  #pragma unroll
  for (int ci=0; ci<CPW; ++ci) {
    int c = wv + ci*NW;
    if (c < nch) {
      int mu = c*16 + col; bool vm = mu < Ms;
      int mus = vm ? mu : 0;
      const ushort* pb = sliceM + (size_t)mus*C;
      if constexpr ((C & 31) != 0) {                     // K-tail
        int kg = (C & ~31) + ko;
        bool v0 = (kg+4 <= C), v1 = (kg+8 <= C);
        s8v bft = ldfrag_m(pb + kg, v0, v1);
        #pragma unroll
        for (int t=0;t<NRT;++t) {
          s8v aft = ldfrag_m(aRow[t] + kg, v0, v1);
          acc[ci][t] = __builtin_amdgcn_mfma_f32_16x16x32_bf16(aft, bft, acc[ci][t], 0,0,0);
        }
      }
      float invBm = invMsl[mus];
      int myq = mus/NG; int my = y0 + myq; int mx = mus - myq*NG;
      #pragma unroll
      for (int t=0;t<NRT;++t) {
        #pragma unroll
        for (int jj=0;jj<4;++jj) {
          int x = t*16 + grp*4 + jj;
          float sim = acc[ci][t][jj] * invAS[x] * invBm;
          bool ok = vm && (x < NG) && (mx - x <= R) && (x - mx <= R);
          if (ok) {
            sumE[t][jj] += __expf(sim);
            if (mz==gz && my==gy && mx==x) lineAln[x] = sim;
          }
        }
      }
    }
  }

  #pragma unroll
  for (int t=0;t<NRT;++t) {
    #pragma unroll
    for (int jj=0;jj<4;++jj) {
      float v = sumE[t][jj];
      v += __shfl_xor(v,1); v += __shfl_xor(v,2); v += __shfl_xor(v,4); v += __shfl_xor(v,8);
      if (col==0) atomicAdd(&sumS[t*16 + grp*4 + jj], v);
    }
  }
  __syncthreads();
  if (tid < NG) {
    float v = sumS[tid];
    if (v != 0.f) atomicAdd(&lineSum[tid], v);
  }
}

__global__ void epilogue_kernel(const float* __restrict__ sumG, const float* __restrict__ alnG,
                                const float* __restrict__ sw, float* __restrict__ out) {
  constexpr int N3 = 54000, N5 = 11664, N9 = 2000;
  constexpr int TOT = N3 + N5 + N9;
  __shared__ float wred[4];
  int idx = blockIdx.x*256 + threadIdx.x;
  float w0 = sw[0], w1 = sw[1], w2 = sw[2];
  float mx = fmaxf(w0, fmaxf(w1, w2));
  float e0 = __expf(w0-mx), e1 = __expf(w1-mx), e2 = __expf(w2-mx);
  float ise = 1.0f/(e0+e1+e2);
  float c = 0.f;
  if (idx < TOT) {
    float coef;
    if (idx < N3)            coef = e0*ise/(float)N3;
    else if (idx < N3+N5)    coef = e1*ise/(float)N5;
    else                     coef = e2*ise/(float)N9;
    c = (__logf(sumG[idx]) - alnG[idx]) * coef;
  }
  #pragma unroll
  for (int o=32;o;o>>=1) c += __shfl_xor(c, o);
  if ((threadIdx.x & 63)==0) wred[threadIdx.x>>6] = c;
  __syncthreads();
  if (threadIdx.x==0) {
    float s = wred[0]+wred[1]+wred[2]+wred[3];
    if (s != 0.f) atomicAdd(out, s);
  }
}

static inline int cdiv(long long a, int b) { return (int)((a + b - 1) / b); }

template<int P, int R, int NRT, int TPB, int KB, int NCHMAX, int CPW, bool AFULL, int CCH>
static void run_scale(const ushort* Yf, const ushort* Ym, ushort* pkF, ushort* pkM,
                      float* invPF, float* invPM, float* sumG, float* alnG, hipStream_t s) {
  constexpr int NG=90/P, N=NG*NG*NG, C=12*P*P*P;
  packn_kernel<P,CCH><<<2*NG*NG, 256, 0, s>>>(Yf, pkF);
  packn_kernel<P,CCH><<<2*NG*NG, 256, 0, s>>>(Ym, pkM);
  normk<C><<<2*N, 64, 0, s>>>(pkF, invPF);
  normk<C><<<2*N, 64, 0, s>>>(pkM, invPM);
  loss_kernel<P,R,NRT,TPB,KB,NCHMAX,CPW,AFULL><<<2*NG*NG*(2*R+1), TPB, 0, s>>>(
      pkF, pkM, invPF, invPM, sumG, alnG);
}

extern "C" void kernel_launch(void* const* d_in, const int* in_sizes, int n_in,
                              void* d_out, int out_size, void* d_ws, size_t ws_size,
                              hipStream_t stream) {
  const float* fixedI  = (const float*)d_in[0];
  const float* movingI = (const float*)d_in[1];
  const float* scale_w = (const float*)d_in[2];
  float* out = (float*)d_out;

  uint8_t* w = (uint8_t*)d_ws;
  float*  smallb = (float*)w;                    // [0]=mv_f [1]=mv_m
  float*  sumG  = (float*)(w + 4096);
  float*  alnG  = sumG + 67664;
  float*  invPF = alnG + 67664;
  float*  invPM = invPF + 67664;
  uint8_t* big = w + (2u<<20);
  float*  A   = (float*)big;                      // 70MB f32 scratch
  float*  Bf  = (float*)(big + 69984000);         // 70MB f32 scratch / PK region
  ushort* pkF = (ushort*)Bf;
  ushort* pkM = pkF + 17496000;
  ushort* Ybf_f = (ushort*)(big + 2*69984000ull);
  ushort* Ybf_m = Ybf_f + 17496000;

  hipMemsetAsync(w, 0, 4096 + 67664*4, stream);
  hipMemsetAsync(d_out, 0, sizeof(float), stream);

  const int gE = cdiv(17496000, 256);
  const int gV = cdiv(1458000, 256);

  diff2z_kernel<<<gE,256,0,stream>>>(fixedI, Bf);
  boxy_kernel<<<gE,256,0,stream>>>(Bf, A);
  boxxmin_kernel<<<gV,256,0,stream>>>(A, Bf, smallb+0);
  finalize_kernel<<<gV,256,0,stream>>>(Bf, Ybf_f, smallb+0);

  diff2z_kernel<<<gE,256,0,stream>>>(movingI, A);
  boxy_kernel<<<gE,256,0,stream>>>(A, Bf);
  boxxmin_kernel<<<gV,256,0,stream>>>(Bf, A, smallb+1);
  finalize_kernel<<<gV,256,0,stream>>>(A, Ybf_m, smallb+1);

  // (P,R,NRT,TPB,KB,NCHMAX,CPW,AFULL,CCH)
  run_scale<3,3,2,256,1,14,4,true ,12>(Ybf_f, Ybf_m, pkF, pkM, invPF,         invPM,         sumG,         alnG,         stream);
  run_scale<5,2,2,128,1, 6,3,false, 6>(Ybf_f, Ybf_m, pkF, pkM, invPF + 54000, invPM + 54000, sumG + 54000, alnG + 54000, stream);
  run_scale<9,1,1,128,8, 2,1,false, 2>(Ybf_f, Ybf_m, pkF, pkM, invPF + 65664, invPM + 65664, sumG + 65664, alnG + 65664, stream);

  epilogue_kernel<<<cdiv(67664,256),256,0,stream>>>(sumG, alnG, scale_w, out);
}

// Round 10
// 1112.302 us; speedup vs baseline: 1.7257x; 1.0414x over previous
//
#include <hip/hip_runtime.h>
#include <hip/hip_bf16.h>
#include <math.h>

#define VOL 729000
#define SL  8100
#define RW  90

typedef __attribute__((ext_vector_type(8))) short s8v;
typedef __attribute__((ext_vector_type(4))) float f32x4;

__device__ __constant__ int c_o1[12][3] = {
  {0,0,-2},{0,-2,0},{0,-2,0},{0,0,2},{0,0,2},{2,0,0},{2,0,0},{2,0,0},{0,2,0},{0,2,0},{0,2,0},{0,2,0}
};
__device__ __constant__ int c_o2[12][3] = {
  {-2,0,0},{-2,0,0},{0,0,-2},{-2,0,0},{0,-2,0},{0,0,-2},{0,-2,0},{0,0,2},{-2,0,0},{0,0,-2},{0,0,2},{2,0,0}
};

__device__ __forceinline__ int clampi(int v, int lo, int hi){ return v<lo?lo:(v>hi?hi:v); }

typedef __attribute__((address_space(3))) uint lds_uint;
typedef __attribute__((address_space(1))) uint glb_uint;
__device__ __forceinline__ void gl_lds16(const ushort* g, ushort* l) {
  __builtin_amdgcn_global_load_lds((const glb_uint*)g, (lds_uint*)l, 16, 0, 0);
}
__device__ __forceinline__ float bf2f(uint u) { return __uint_as_float(u << 16); }

__global__ void diff2z_kernel(const float* __restrict__ img, float* __restrict__ out) {
  int idx = blockIdx.x*256 + threadIdx.x;
  if (idx >= 2*12*VOL) return;
  int vox = idx % VOL; int ct = idx / VOL; int t = ct % 12, b = ct / 12;
  int z = vox / SL; int r = vox % SL; int y = r / RW; int x = r % RW;
  const float* im = img + (size_t)b*VOL;
  int o1z=c_o1[t][0], o1y=c_o1[t][1], o1x=c_o1[t][2];
  int o2z=c_o2[t][0], o2y=c_o2[t][1], o2x=c_o2[t][2];
  int y1 = clampi(y+o1y,0,89), x1 = clampi(x+o1x,0,89);
  int y2 = clampi(y+o2y,0,89), x2 = clampi(x+o2x,0,89);
  float s = 0.f;
  #pragma unroll
  for (int d=-2; d<=2; ++d) {
    int zz = clampi(z+d,0,89);
    int z1 = clampi(zz+o1z,0,89), z2 = clampi(zz+o2z,0,89);
    float dv = im[z1*SL+y1*RW+x1] - im[z2*SL+y2*RW+x2];
    s += dv*dv;
  }
  out[idx] = s;
}

__global__ void boxy_kernel(const float* __restrict__ in, float* __restrict__ out) {
  int idx = blockIdx.x*256 + threadIdx.x;
  if (idx >= 2*12*VOL) return;
  int vox = idx % VOL; int bc = idx / VOL;
  int z = vox / SL; int r = vox % SL; int y = r / RW; int x = r % RW;
  const float* p = in + (size_t)bc*VOL + (size_t)z*SL + x;
  float s = 0.f;
  #pragma unroll
  for (int d=-2; d<=2; ++d) { int yc = clampi(y+d,0,89); s += p[yc*RW]; }
  out[idx] = s;
}

__global__ void boxxmin_kernel(const float* __restrict__ in, float* __restrict__ outPre,
                               float* __restrict__ mvsum) {
  __shared__ float red;
  if (threadIdx.x == 0) red = 0.f;
  __syncthreads();
  int idx = blockIdx.x*256 + threadIdx.x;
  float mv = 0.f;
  if (idx < 2*VOL) {
    int b = idx / VOL; int vox = idx % VOL;
    int z = vox / SL; int r = vox % SL; int y = r / RW; int x = r % RW;
    const float* base = in + (size_t)b*12*VOL + (size_t)z*SL + (size_t)y*RW;
    float s[12]; float mn = 3.4e38f;
    #pragma unroll
    for (int c=0;c<12;++c) {
      const float* pc = base + (size_t)c*VOL;
      float t = 0.f;
      #pragma unroll
      for (int d=-2;d<=2;++d) { int xc = clampi(x+d,0,89); t += pc[xc]; }
      t *= (1.0f/125.0f);
      s[c] = t; mn = fminf(mn, t);
    }
    float* ob = outPre + (size_t)b*12*VOL + vox;
    #pragma unroll
    for (int c=0;c<12;++c) { float pre = s[c]-mn; ob[(size_t)c*VOL] = pre; mv += pre; }
    mv *= (1.0f/12.0f);
  }
  #pragma unroll
  for (int o=32;o;o>>=1) mv += __shfl_xor(mv, o);
  if ((threadIdx.x & 63)==0 && mv != 0.f) atomicAdd(&red, mv);
  __syncthreads();
  if (threadIdx.x==0) atomicAdd(mvsum, red);
}

__global__ void finalize_kernel(const float* __restrict__ pre, ushort* __restrict__ out,
                                const float* __restrict__ mvsum) {
  int idx = blockIdx.x*256 + threadIdx.x;
  if (idx >= 2*VOL) return;
  int b = idx / VOL; int vox = idx % VOL;
  const float* base = pre + (size_t)b*12*VOL + vox;
  ushort* ob = out + (size_t)b*12*VOL + vox;
  float s[12]; float mv = 0.f;
  #pragma unroll
  for (int c=0;c<12;++c) { s[c] = base[(size_t)c*VOL]; mv += s[c]; }
  mv *= (1.0f/12.0f);
  float mm = *mvsum * (1.0f/1458000.0f);
  float mvc = fminf(fmaxf(mv, mm*0.001f), mm*1000.0f);
  float inv = 1.0f / mvc;
  #pragma unroll
  for (int c=0;c<12;++c) {
    __hip_bfloat16 h = __float2bfloat16(__expf(-s[c]*inv));
    ob[(size_t)c*VOL] = *(ushort*)&h;
  }
}

template<int P, int CCH>
__global__ __launch_bounds__(256) void packn_kernel(const ushort* __restrict__ Ybf,
                                                    ushort* __restrict__ pk) {
  constexpr int NG=90/P, N=NG*NG*NG, C=12*P*P*P;
  constexpr int P2=P*P, P3=P*P*P;
  constexpr int ROWS = CCH*P2;
  constexpr int HALF = CCH*P3/2;
  __shared__ uint slabU[ROWS*48];
  int blk = blockIdx.x;
  int gy = blk % NG; int t1 = blk / NG; int gz = t1 % NG; int b = t1 / NG;
  int tid = threadIdx.x;
  size_t obase = ((size_t)b*N + ((size_t)gz*NG + gy)*NG) * C;
  for (int c0 = 0; c0 < 12; c0 += CCH) {
    if (c0) __syncthreads();
    for (int i = tid; i < ROWS*45; i += 256) {
      int r = i/45, xu = i - r*45;
      int c = c0 + r/P2; int rr = r % P2; int dz = rr/P, dy = rr - dz*P;
      const ushort* src = Ybf + ((size_t)(b*12 + c)*VOL + (size_t)(gz*P+dz)*SL + (size_t)(gy*P+dy)*RW);
      slabU[r*48 + xu] = *(const uint*)(src + 2*xu);
    }
    __syncthreads();
    const ushort* slab = (const ushort*)slabU;
    for (int i = tid; i < NG*HALF; i += 256) {
      int d = i/HALF, j2 = i - d*HALF;
      int k = 2*j2;
      int cc = k/P3; int rem = k - cc*P3;
      int dz = rem/P2; int r2 = rem - dz*P2; int dy = r2/P; int dx = r2 - dy*P;
      uint lo = slab[((cc*P + dz)*P + dy)*96 + d*P + dx];
      int k1 = k+1;
      int cc1 = k1/P3; int rem1 = k1 - cc1*P3;
      int dz1 = rem1/P2; int r21 = rem1 - dz1*P2; int dy1 = r21/P; int dx1 = r21 - dy1*P;
      uint hi = slab[((cc1*P + dz1)*P + dy1)*96 + d*P + dx1];
      *(uint*)(pk + obase + (size_t)d*C + c0*P3 + k) = lo | (hi << 16);
    }
  }
}

template<int C>
__global__ __launch_bounds__(64) void normk(const ushort* __restrict__ pk,
                                            float* __restrict__ inv) {
  int d = blockIdx.x; int lane = threadIdx.x;
  const uint* p = (const uint*)(pk + (size_t)d*C);
  float ss = 0.f;
  for (int i = lane; i < C/2; i += 64) {
    uint u = p[i];
    float a = bf2f(u & 0xffffu), bb = bf2f(u >> 16);
    ss += a*a + bb*bb;
  }
  #pragma unroll
  for (int o=32;o;o>>=1) ss += __shfl_xor(ss, o);
  if (lane==0) inv[d] = 1.0f / fmaxf(sqrtf(ss), 1e-12f);
}

union FragU { s8v s; uint u[4]; };
__device__ __forceinline__ s8v ldfrag_m(const ushort* p, bool v0, bool v1) {
  FragU f;
  if (v0) { uint2 a = *(const uint2*)p;     f.u[0]=a.x; f.u[1]=a.y; } else { f.u[0]=0; f.u[1]=0; }
  if (v1) { uint2 b = *(const uint2*)(p+4); f.u[2]=b.x; f.u[3]=b.y; } else { f.u[2]=0; f.u[3]=0; }
  return f.s;
}

// R9 structure + T3/T4 pipeline: counted vmcnt (never 0 in main loop) + raw
// s_barrier. Staging counts made exactly uniform per wave (TCNT) via clamped
// duplicate stages (same-value writes, benign).
template<int P, int R, int NRT, int TPB, int KB, int NCHMAX, int CPW, bool AFULL>
__global__ __launch_bounds__(TPB) void loss_kernel(
    const ushort* __restrict__ pkF, const ushort* __restrict__ pkM,
    const float* __restrict__ invF, const float* __restrict__ invM,
    float* __restrict__ sumG, float* __restrict__ alnG) {
  constexpr int NG=90/P, N=NG*NG*NG, C=12*P*P*P;
  constexpr int NW=TPB/64, WZ=2*R+1;
  constexpr int KS4 = (C & ~31)/32;          // 10 / 46 / 273
  constexpr int NPH = (KS4 + KB - 1)/KB;
  constexpr int NROWS = NRT*16;
  constexpr int ASLOT = AFULL ? 0 : NRT;
  constexpr int SLOTS = ASLOT + NCHMAX;
  constexpr int AFT = AFULL ? KS4*NRT : 1;
  constexpr int TOTS = ((SLOTS*KB + NW - 1)/NW)*NW;   // padded tiles/phase
  constexpr int TCNT = TOTS/NW;                       // loads per wave per phase
  static_assert(NROWS >= NG, "rows cover x line");
  static_assert(CPW*NW >= NCHMAX, "chunk coverage");
  static_assert(!AFULL || (KS4*NRT) % NW == 0, "uniform aT staging");
  __shared__ float sumS[NROWS];
  __shared__ float invAS[NROWS];
  __shared__ __align__(16) ushort aT[AFT*512];
  __shared__ __align__(16) ushort bP[2][SLOTS*KB*512];

  int nwg = gridDim.x;
  int q = nwg >> 3, r8 = nwg & 7;
  int xcd = blockIdx.x & 7, sidx = blockIdx.x >> 3;
  int lid = (xcd < r8 ? xcd*(q+1) : r8*(q+1) + (xcd - r8)*q) + sidx;
  int j = lid % WZ; int t1 = lid / WZ;
  int gy = t1 % NG; t1 /= NG;
  int mz = t1 % NG; int b = t1 / NG;
  int gz = mz - R + j;
  if (gz < 0 || gz >= NG) return;
  int tid = threadIdx.x; int lane = tid & 63; int wv = tid >> 6;
  int col = lane & 15, grp = lane >> 4;
  const int ko = grp*8;
  for (int i = tid; i < NROWS; i += TPB) {
    sumS[i] = 0.f;
    invAS[i] = (i < NG) ? invF[(size_t)b*N + ((size_t)gz*NG + gy)*NG + i] : 0.f;
  }

  size_t baseF = ((size_t)b*N + ((size_t)gz*NG + gy)*NG) * C;
  const ushort* aRow[NRT];
  #pragma unroll
  for (int t=0;t<NRT;++t) {
    int row = t*16 + col; if (row > NG-1) row = NG-1;
    aRow[t] = pkF + baseF + (size_t)row*C;
  }
  int y0 = max(gy-R,0), y1 = min(gy+R,NG-1);
  int wy = y1-y0+1;
  int Ms = wy*NG;
  int nch = (Ms+15)>>4;
  const ushort* sliceM = pkM + ((size_t)b*N + ((size_t)mz*NG + y0)*NG) * C;
  const float* invMsl  = invM + (size_t)b*N + ((size_t)mz*NG + y0)*NG;
  float* lineSum = sumG + (size_t)b*N + ((size_t)gz*NG + gy)*NG;
  float* lineAln = alnG + (size_t)b*N + ((size_t)gz*NG + gy)*NG;

  // uniform-count stage: each wave issues exactly TCNT gl_lds16
  auto stage = [&](int ph, ushort* dst) {
    int tb = ph*KB;
    #pragma unroll
    for (int k = 0; k < TCNT; ++k) {
      int i2 = wv + k*NW;
      int ii = i2 < SLOTS*KB ? i2 : SLOTS*KB - 1;   // pad clamp (dup write)
      int slot = ii / KB, s = ii - slot*KB;
      int ks = tb + s; if (ks >= KS4) ks = KS4 - 1; // clamp (dup write)
      const ushort* src;
      if (slot < ASLOT) {
        src = aRow[slot] + (size_t)ks*32 + ko;
      } else {
        int c = slot - ASLOT; if (c > nch-1) c = nch-1;
        int di = c*16 + col; if (di > Ms-1) di = Ms-1;
        src = sliceM + (size_t)di*C + (size_t)ks*32 + ko;
      }
      gl_lds16(src, dst + ii*512);
    }
  };

  if constexpr (AFULL) {
    #pragma unroll
    for (int k = 0; k < (KS4*NRT)/NW; ++k) {
      int i2 = wv + k*NW;
      int ks = i2/NRT, t = i2 - ks*NRT;
      gl_lds16(aRow[t] + (size_t)ks*32 + ko, aT + i2*512);
    }
  }
  stage(0, bP[0]);

  f32x4 acc[CPW][NRT];
  #pragma unroll
  for (int ci=0;ci<CPW;++ci)
    #pragma unroll
    for (int t=0;t<NRT;++t) acc[ci][t] = (f32x4){0.f,0.f,0.f,0.f};

  for (int ph = 0; ph < NPH; ++ph) {
    if (ph+1 < NPH) {
      stage(ph+1, bP[(ph+1)&1]);
      asm volatile("s_waitcnt vmcnt(%0)" :: "i"(TCNT) : "memory");
    } else {
      asm volatile("s_waitcnt vmcnt(0)" ::: "memory");
    }
    __builtin_amdgcn_sched_barrier(0);
    asm volatile("s_barrier" ::: "memory");       // bP[ph&1] fully staged
    const ushort* buf = bP[ph&1];
    __builtin_amdgcn_s_setprio(1);
    #pragma unroll
    for (int s = 0; s < KB; ++s) {
      int ks = ph*KB + s;
      if (ks >= KS4) break;
      s8v af[NRT];
      #pragma unroll
      for (int t=0;t<NRT;++t) {
        const ushort* ap;
        if constexpr (AFULL) ap = aT + (size_t)(ks*NRT + t)*512 + lane*8;
        else                 ap = buf + (t*KB + s)*512 + lane*8;
        af[t] = *(const s8v*)ap;
      }
      #pragma unroll
      for (int ci=0; ci<CPW; ++ci) {
        int c = wv + ci*NW;
        if (c < nch) {                                   // wave-uniform
          s8v bf = *(const s8v*)(buf + ((ASLOT + c)*KB + s)*512 + lane*8);
          #pragma unroll
          for (int t=0;t<NRT;++t)
            acc[ci][t] = __builtin_amdgcn_mfma_f32_16x16x32_bf16(af[t], bf, acc[ci][t], 0,0,0);
        }
      }
    }
    __builtin_amdgcn_s_setprio(0);
    asm volatile("s_barrier" ::: "memory");       // all done reading bP[ph&1]
  }

  float sumE[NRT][4];
  #pragma unroll
  for (int t=0;t<NRT;++t) { sumE[t][0]=0.f; sumE[t][1]=0.f; sumE[t][2]=0.f; sumE[t][3]=0.f; }

  #pragma unroll
  for (int ci=0; ci<CPW; ++ci) {
    int c = wv + ci*NW;
    if (c < nch) {
      int mu = c*16 + col; bool vm = mu < Ms;
      int mus = vm ? mu : 0;
      const ushort* pb = sliceM + (size_t)mus*C;
      if constexpr ((C & 31) != 0) {                     // K-tail
        int kg = (C & ~31) + ko;
        bool v0 = (kg+4 <= C), v1 = (kg+8 <= C);
        s8v bft = ldfrag_m(pb + kg, v0, v1);
        #pragma unroll
        for (int t=0;t<NRT;++t) {
          s8v aft = ldfrag_m(aRow[t] + kg, v0, v1);
          acc[ci][t] = __builtin_amdgcn_mfma_f32_16x16x32_bf16(aft, bft, acc[ci][t], 0,0,0);
        }
      }
      float invBm = invMsl[mus];
      int myq = mus/NG; int my = y0 + myq; int mx = mus - myq*NG;
      #pragma unroll
      for (int t=0;t<NRT;++t) {
        #pragma unroll
        for (int jj=0;jj<4;++jj) {
          int x = t*16 + grp*4 + jj;
          float sim = acc[ci][t][jj] * invAS[x] * invBm;
          bool ok = vm && (x < NG) && (mx - x <= R) && (x - mx <= R);
          if (ok) {
            sumE[t][jj] += __expf(sim);
            if (mz==gz && my==gy && mx==x) lineAln[x] = sim;
          }
        }
      }
    }
  }

  #pragma unroll
  for (int t=0;t<NRT;++t) {
    #pragma unroll
    for (int jj=0;jj<4;++jj) {
      float v = sumE[t][jj];
      v += __shfl_xor(v,1); v += __shfl_xor(v,2); v += __shfl_xor(v,4); v += __shfl_xor(v,8);
      if (col==0) atomicAdd(&sumS[t*16 + grp*4 + jj], v);
    }
  }
  __syncthreads();
  if (tid < NG) {
    float v = sumS[tid];
    if (v != 0.f) atomicAdd(&lineSum[tid], v);
  }
}

__global__ void epilogue_kernel(const float* __restrict__ sumG, const float* __restrict__ alnG,
                                const float* __restrict__ sw, float* __restrict__ out) {
  constexpr int N3 = 54000, N5 = 11664, N9 = 2000;
  constexpr int TOT = N3 + N5 + N9;
  __shared__ float wred[4];
  int idx = blockIdx.x*256 + threadIdx.x;
  float w0 = sw[0], w1 = sw[1], w2 = sw[2];
  float mx = fmaxf(w0, fmaxf(w1, w2));
  float e0 = __expf(w0-mx), e1 = __expf(w1-mx), e2 = __expf(w2-mx);
  float ise = 1.0f/(e0+e1+e2);
  float c = 0.f;
  if (idx < TOT) {
    float coef;
    if (idx < N3)            coef = e0*ise/(float)N3;
    else if (idx < N3+N5)    coef = e1*ise/(float)N5;
    else                     coef = e2*ise/(float)N9;
    c = (__logf(sumG[idx]) - alnG[idx]) * coef;
  }
  #pragma unroll
  for (int o=32;o;o>>=1) c += __shfl_xor(c, o);
  if ((threadIdx.x & 63)==0) wred[threadIdx.x>>6] = c;
  __syncthreads();
  if (threadIdx.x==0) {
    float s = wred[0]+wred[1]+wred[2]+wred[3];
    if (s != 0.f) atomicAdd(out, s);
  }
}

static inline int cdiv(long long a, int b) { return (int)((a + b - 1) / b); }

template<int P, int R, int NRT, int TPB, int KB, int NCHMAX, int CPW, bool AFULL, int CCH>
static void run_scale(const ushort* Yf, const ushort* Ym, ushort* pkF, ushort* pkM,
                      float* invPF, float* invPM, float* sumG, float* alnG, hipStream_t s) {
  constexpr int NG=90/P, N=NG*NG*NG, C=12*P*P*P;
  packn_kernel<P,CCH><<<2*NG*NG, 256, 0, s>>>(Yf, pkF);
  packn_kernel<P,CCH><<<2*NG*NG, 256, 0, s>>>(Ym, pkM);
  normk<C><<<2*N, 64, 0, s>>>(pkF, invPF);
  normk<C><<<2*N, 64, 0, s>>>(pkM, invPM);
  loss_kernel<P,R,NRT,TPB,KB,NCHMAX,CPW,AFULL><<<2*NG*NG*(2*R+1), TPB, 0, s>>>(
      pkF, pkM, invPF, invPM, sumG, alnG);
}

extern "C" void kernel_launch(void* const* d_in, const int* in_sizes, int n_in,
                              void* d_out, int out_size, void* d_ws, size_t ws_size,
                              hipStream_t stream) {
  const float* fixedI  = (const float*)d_in[0];
  const float* movingI = (const float*)d_in[1];
  const float* scale_w = (const float*)d_in[2];
  float* out = (float*)d_out;

  uint8_t* w = (uint8_t*)d_ws;
  float*  smallb = (float*)w;                    // [0]=mv_f [1]=mv_m
  float*  sumG  = (float*)(w + 4096);
  float*  alnG  = sumG + 67664;
  float*  invPF = alnG + 67664;
  float*  invPM = invPF + 67664;
  uint8_t* big = w + (2u<<20);
  float*  A   = (float*)big;                      // 70MB f32 scratch
  float*  Bf  = (float*)(big + 69984000);         // 70MB f32 scratch / PK region
  ushort* pkF = (ushort*)Bf;
  ushort* pkM = pkF + 17496000;
  ushort* Ybf_f = (ushort*)(big + 2*69984000ull);
  ushort* Ybf_m = Ybf_f + 17496000;

  hipMemsetAsync(w, 0, 4096 + 67664*4, stream);
  hipMemsetAsync(d_out, 0, sizeof(float), stream);

  const int gE = cdiv(17496000, 256);
  const int gV = cdiv(1458000, 256);

  diff2z_kernel<<<gE,256,0,stream>>>(fixedI, Bf);
  boxy_kernel<<<gE,256,0,stream>>>(Bf, A);
  boxxmin_kernel<<<gV,256,0,stream>>>(A, Bf, smallb+0);
  finalize_kernel<<<gV,256,0,stream>>>(Bf, Ybf_f, smallb+0);

  diff2z_kernel<<<gE,256,0,stream>>>(movingI, A);
  boxy_kernel<<<gE,256,0,stream>>>(A, Bf);
  boxxmin_kernel<<<gV,256,0,stream>>>(Bf, A, smallb+1);
  finalize_kernel<<<gV,256,0,stream>>>(A, Ybf_m, smallb+1);

  // (P,R,NRT,TPB,KB,NCHMAX,CPW,AFULL,CCH)
  run_scale<3,3,2,256,1,14,4,true ,12>(Ybf_f, Ybf_m, pkF, pkM, invPF,         invPM,         sumG,         alnG,         stream);
  run_scale<5,2,2,128,1, 6,3,false, 6>(Ybf_f, Ybf_m, pkF, pkM, invPF + 54000, invPM + 54000, sumG + 54000, alnG + 54000, stream);
  run_scale<9,1,1,128,8, 2,1,false, 2>(Ybf_f, Ybf_m, pkF, pkM, invPF + 65664, invPM + 65664, sumG + 65664, alnG + 65664, stream);

  epilogue_kernel<<<cdiv(67664,256),256,0,stream>>>(sumG, alnG, scale_w, out);
}

// Round 11
// 1051.529 us; speedup vs baseline: 1.8255x; 1.0578x over previous
//
#include <hip/hip_runtime.h>
#include <hip/hip_bf16.h>
#include <math.h>

#define VOL 729000
#define SL  8100
#define RW  90

typedef __attribute__((ext_vector_type(8))) short s8v;
typedef __attribute__((ext_vector_type(4))) float f32x4;

__device__ __constant__ int c_o1[12][3] = {
  {0,0,-2},{0,-2,0},{0,-2,0},{0,0,2},{0,0,2},{2,0,0},{2,0,0},{2,0,0},{0,2,0},{0,2,0},{0,2,0},{0,2,0}
};
__device__ __constant__ int c_o2[12][3] = {
  {-2,0,0},{-2,0,0},{0,0,-2},{-2,0,0},{0,-2,0},{0,0,-2},{0,-2,0},{0,0,2},{-2,0,0},{0,0,-2},{0,0,2},{2,0,0}
};

__device__ __forceinline__ int clampi(int v, int lo, int hi){ return v<lo?lo:(v>hi?hi:v); }

typedef __attribute__((address_space(3))) uint lds_uint;
typedef __attribute__((address_space(1))) uint glb_uint;
__device__ __forceinline__ void gl_lds16(const ushort* g, ushort* l) {
  __builtin_amdgcn_global_load_lds((const glb_uint*)g, (lds_uint*)l, 16, 0, 0);
}
__device__ __forceinline__ float bf2f(uint u) { return __uint_as_float(u << 16); }

__global__ void diff2z_kernel(const float* __restrict__ img, float* __restrict__ out) {
  int idx = blockIdx.x*256 + threadIdx.x;
  if (idx >= 2*12*VOL) return;
  int vox = idx % VOL; int ct = idx / VOL; int t = ct % 12, b = ct / 12;
  int z = vox / SL; int r = vox % SL; int y = r / RW; int x = r % RW;
  const float* im = img + (size_t)b*VOL;
  int o1z=c_o1[t][0], o1y=c_o1[t][1], o1x=c_o1[t][2];
  int o2z=c_o2[t][0], o2y=c_o2[t][1], o2x=c_o2[t][2];
  int y1 = clampi(y+o1y,0,89), x1 = clampi(x+o1x,0,89);
  int y2 = clampi(y+o2y,0,89), x2 = clampi(x+o2x,0,89);
  float s = 0.f;
  #pragma unroll
  for (int d=-2; d<=2; ++d) {
    int zz = clampi(z+d,0,89);
    int z1 = clampi(zz+o1z,0,89), z2 = clampi(zz+o2z,0,89);
    float dv = im[z1*SL+y1*RW+x1] - im[z2*SL+y2*RW+x2];
    s += dv*dv;
  }
  out[idx] = s;
}

__global__ void boxy_kernel(const float* __restrict__ in, float* __restrict__ out) {
  int idx = blockIdx.x*256 + threadIdx.x;
  if (idx >= 2*12*VOL) return;
  int vox = idx % VOL; int bc = idx / VOL;
  int z = vox / SL; int r = vox % SL; int y = r / RW; int x = r % RW;
  const float* p = in + (size_t)bc*VOL + (size_t)z*SL + x;
  float s = 0.f;
  #pragma unroll
  for (int d=-2; d<=2; ++d) { int yc = clampi(y+d,0,89); s += p[yc*RW]; }
  out[idx] = s;
}

__global__ void boxxmin_kernel(const float* __restrict__ in, float* __restrict__ outPre,
                               float* __restrict__ mvsum) {
  __shared__ float red;
  if (threadIdx.x == 0) red = 0.f;
  __syncthreads();
  int idx = blockIdx.x*256 + threadIdx.x;
  float mv = 0.f;
  if (idx < 2*VOL) {
    int b = idx / VOL; int vox = idx % VOL;
    int z = vox / SL; int r = vox % SL; int y = r / RW; int x = r % RW;
    const float* base = in + (size_t)b*12*VOL + (size_t)z*SL + (size_t)y*RW;
    float s[12]; float mn = 3.4e38f;
    #pragma unroll
    for (int c=0;c<12;++c) {
      const float* pc = base + (size_t)c*VOL;
      float t = 0.f;
      #pragma unroll
      for (int d=-2;d<=2;++d) { int xc = clampi(x+d,0,89); t += pc[xc]; }
      t *= (1.0f/125.0f);
      s[c] = t; mn = fminf(mn, t);
    }
    float* ob = outPre + (size_t)b*12*VOL + vox;
    #pragma unroll
    for (int c=0;c<12;++c) { float pre = s[c]-mn; ob[(size_t)c*VOL] = pre; mv += pre; }
    mv *= (1.0f/12.0f);
  }
  #pragma unroll
  for (int o=32;o;o>>=1) mv += __shfl_xor(mv, o);
  if ((threadIdx.x & 63)==0 && mv != 0.f) atomicAdd(&red, mv);
  __syncthreads();
  if (threadIdx.x==0) atomicAdd(mvsum, red);
}

__global__ void finalize_kernel(const float* __restrict__ pre, ushort* __restrict__ out,
                                const float* __restrict__ mvsum) {
  int idx = blockIdx.x*256 + threadIdx.x;
  if (idx >= 2*VOL) return;
  int b = idx / VOL; int vox = idx % VOL;
  const float* base = pre + (size_t)b*12*VOL + vox;
  ushort* ob = out + (size_t)b*12*VOL + vox;
  float s[12]; float mv = 0.f;
  #pragma unroll
  for (int c=0;c<12;++c) { s[c] = base[(size_t)c*VOL]; mv += s[c]; }
  mv *= (1.0f/12.0f);
  float mm = *mvsum * (1.0f/1458000.0f);
  float mvc = fminf(fmaxf(mv, mm*0.001f), mm*1000.0f);
  float inv = 1.0f / mvc;
  #pragma unroll
  for (int c=0;c<12;++c) {
    __hip_bfloat16 h = __float2bfloat16(__expf(-s[c]*inv));
    ob[(size_t)c*VOL] = *(ushort*)&h;
  }
}

template<int P, int CCH>
__global__ __launch_bounds__(256) void packn_kernel(const ushort* __restrict__ Ybf,
                                                    ushort* __restrict__ pk) {
  constexpr int NG=90/P, N=NG*NG*NG, C=12*P*P*P;
  constexpr int P2=P*P, P3=P*P*P;
  constexpr int ROWS = CCH*P2;
  constexpr int HALF = CCH*P3/2;
  __shared__ uint slabU[ROWS*48];
  int blk = blockIdx.x;
  int gy = blk % NG; int t1 = blk / NG; int gz = t1 % NG; int b = t1 / NG;
  int tid = threadIdx.x;
  size_t obase = ((size_t)b*N + ((size_t)gz*NG + gy)*NG) * C;
  for (int c0 = 0; c0 < 12; c0 += CCH) {
    if (c0) __syncthreads();
    for (int i = tid; i < ROWS*45; i += 256) {
      int r = i/45, xu = i - r*45;
      int c = c0 + r/P2; int rr = r % P2; int dz = rr/P, dy = rr - dz*P;
      const ushort* src = Ybf + ((size_t)(b*12 + c)*VOL + (size_t)(gz*P+dz)*SL + (size_t)(gy*P+dy)*RW);
      slabU[r*48 + xu] = *(const uint*)(src + 2*xu);
    }
    __syncthreads();
    const ushort* slab = (const ushort*)slabU;
    for (int i = tid; i < NG*HALF; i += 256) {
      int d = i/HALF, j2 = i - d*HALF;
      int k = 2*j2;
      int cc = k/P3; int rem = k - cc*P3;
      int dz = rem/P2; int r2 = rem - dz*P2; int dy = r2/P; int dx = r2 - dy*P;
      uint lo = slab[((cc*P + dz)*P + dy)*96 + d*P + dx];
      int k1 = k+1;
      int cc1 = k1/P3; int rem1 = k1 - cc1*P3;
      int dz1 = rem1/P2; int r21 = rem1 - dz1*P2; int dy1 = r21/P; int dx1 = r21 - dy1*P;
      uint hi = slab[((cc1*P + dz1)*P + dy1)*96 + d*P + dx1];
      *(uint*)(pk + obase + (size_t)d*C + c0*P3 + k) = lo | (hi << 16);
    }
  }
}

template<int C>
__global__ __launch_bounds__(64) void normk(const ushort* __restrict__ pk,
                                            float* __restrict__ inv) {
  int d = blockIdx.x; int lane = threadIdx.x;
  const uint* p = (const uint*)(pk + (size_t)d*C);
  float ss = 0.f;
  for (int i = lane; i < C/2; i += 64) {
    uint u = p[i];
    float a = bf2f(u & 0xffffu), bb = bf2f(u >> 16);
    ss += a*a + bb*bb;
  }
  #pragma unroll
  for (int o=32;o;o>>=1) ss += __shfl_xor(ss, o);
  if (lane==0) inv[d] = 1.0f / fmaxf(sqrtf(ss), 1e-12f);
}

union FragU { s8v s; uint u[4]; };
__device__ __forceinline__ s8v ldfrag_m(const ushort* p, bool v0, bool v1) {
  FragU f;
  if (v0) { uint2 a = *(const uint2*)p;     f.u[0]=a.x; f.u[1]=a.y; } else { f.u[0]=0; f.u[1]=0; }
  if (v1) { uint2 b = *(const uint2*)(p+4); f.u[2]=b.x; f.u[3]=b.y; } else { f.u[2]=0; f.u[3]=0; }
  return f.s;
}

// Merged-line loss: block = (b, mz, gy, jg) computes JM gz lines (gz = mz-R+jg*JM+gzi)
// against ONE staged B-slice (plane mz, y-window of gy). M-rows = AT=JM*XT tiles:
// row -> (gzi = at/XT, x = (at%XT)*16 + sub). Counted-vmcnt phase pipeline (T3/T4),
// frag-native LDS tiles (linear ds_read_b128), raw descriptors (sim scaled by invA*invB).
template<int P, int R, int JM, int XT, int TPB, int KB, int NCHMAX, int CPW>
__global__ __launch_bounds__(TPB) void loss_kernel(
    const ushort* __restrict__ pkF, const ushort* __restrict__ pkM,
    const float* __restrict__ invF, const float* __restrict__ invM,
    float* __restrict__ sumG, float* __restrict__ alnG) {
  constexpr int NG=90/P, N=NG*NG*NG, C=12*P*P*P;
  constexpr int NW=TPB/64;
  constexpr int AT=JM*XT;
  constexpr int KS4=(C & ~31)/32;
  constexpr int NPH=(KS4+KB-1)/KB;
  constexpr int NROWS=AT*16;
  constexpr int NJG=(2*R+1+JM-1)/JM;
  constexpr int SLOTS=(AT+NCHMAX)*KB;
  constexpr int TOTS=((SLOTS+NW-1)/NW)*NW;
  constexpr int TCNT=TOTS/NW;
  static_assert(XT*16 >= NG, "x tiles cover line");
  static_assert(CPW*NW >= NCHMAX, "chunk coverage");
  __shared__ float sumS[NROWS];
  __shared__ float invAS[NROWS];
  __shared__ __align__(16) ushort bP[2][SLOTS*512];

  int nwg = gridDim.x;
  int q = nwg >> 3, r8 = nwg & 7;
  int xcd = blockIdx.x & 7, sidx = blockIdx.x >> 3;
  int lid = (xcd < r8 ? xcd*(q+1) : r8*(q+1) + (xcd - r8)*q) + sidx;
  int jg = lid % NJG; int t1 = lid / NJG;
  int gy = t1 % NG; t1 /= NG;
  int mz = t1 % NG; int b = t1 / NG;
  int gz0 = mz - R + jg*JM;
  // line validity (arithmetic, no arrays)
  bool any = false;
  #pragma unroll
  for (int g=0; g<JM; ++g)
    any |= (jg*JM+g <= 2*R) && ((unsigned)(gz0+g) < (unsigned)NG);
  if (!any) return;

  int tid = threadIdx.x; int lane = tid & 63; int wv = tid >> 6;
  int col = lane & 15, grp = lane >> 4;
  const int ko = grp*8;

  const ushort* aRow[AT];
  #pragma unroll
  for (int at=0; at<AT; ++at) {
    int gzi = at/XT, xt = at%XT;
    int gzc = clampi(gz0+gzi, 0, NG-1);
    int xd = xt*16 + col; if (xd > NG-1) xd = NG-1;
    aRow[at] = pkF + ((size_t)b*N + ((size_t)gzc*NG + gy)*NG + xd) * C;
  }
  for (int i = tid; i < NROWS; i += TPB) {
    sumS[i] = 0.f;
    int at = i >> 4, sub = i & 15;
    int gzi = at/XT, x = (at%XT)*16 + sub;
    bool lvr = (jg*JM+gzi <= 2*R) && ((unsigned)(gz0+gzi) < (unsigned)NG) && (x < NG);
    invAS[i] = lvr ? invF[(size_t)b*N + ((size_t)(gz0+gzi)*NG + gy)*NG + x] : 0.f;
  }

  int y0 = max(gy-R,0), y1 = min(gy+R,NG-1);
  int wy = y1-y0+1;
  int Ms = wy*NG;
  int nch = (Ms+15)>>4;
  const ushort* sliceM = pkM + ((size_t)b*N + ((size_t)mz*NG + y0)*NG) * C;
  const float* invMsl  = invM + (size_t)b*N + ((size_t)mz*NG + y0)*NG;

  // uniform-count stage: each wave issues exactly TCNT gl_lds16
  auto stage = [&](int ph, ushort* dst) {
    int tb = ph*KB;
    #pragma unroll
    for (int k = 0; k < TCNT; ++k) {
      int i2 = wv + k*NW;
      int ii = i2 < SLOTS ? i2 : SLOTS-1;
      int slot = ii / KB, s = ii - slot*KB;
      int ks = tb + s; if (ks >= KS4) ks = KS4-1;
      const ushort* src;
      if (slot < AT) {
        src = aRow[slot] + (size_t)ks*32 + ko;
      } else {
        int c = slot - AT; if (c > nch-1) c = nch-1;
        int di = c*16 + col; if (di > Ms-1) di = Ms-1;
        src = sliceM + (size_t)di*C + (size_t)ks*32 + ko;
      }
      gl_lds16(src, dst + ii*512);
    }
  };

  stage(0, bP[0]);
  __syncthreads();          // drains prologue stage + invAS/sumS writes

  f32x4 acc[CPW][AT];
  #pragma unroll
  for (int ci=0;ci<CPW;++ci)
    #pragma unroll
    for (int at=0;at<AT;++at) acc[ci][at] = (f32x4){0.f,0.f,0.f,0.f};

  for (int ph = 0; ph < NPH; ++ph) {
    if (ph+1 < NPH) {
      stage(ph+1, bP[(ph+1)&1]);
      asm volatile("s_waitcnt vmcnt(%0)" :: "i"(TCNT) : "memory");
    } else {
      asm volatile("s_waitcnt vmcnt(0)" ::: "memory");
    }
    __builtin_amdgcn_sched_barrier(0);
    asm volatile("s_barrier" ::: "memory");       // phase data staged by all waves
    const ushort* buf = bP[ph&1];
    __builtin_amdgcn_s_setprio(1);
    #pragma unroll
    for (int s = 0; s < KB; ++s) {
      int ks = ph*KB + s;
      if (ks >= KS4) break;
      s8v bf[CPW];
      #pragma unroll
      for (int ci=0; ci<CPW; ++ci) {
        int c = wv + ci*NW;
        if (c < nch) bf[ci] = *(const s8v*)(buf + ((AT + c)*KB + s)*512 + lane*8);
      }
      #pragma unroll
      for (int at=0; at<AT; ++at) {
        s8v af = *(const s8v*)(buf + (at*KB + s)*512 + lane*8);
        #pragma unroll
        for (int ci=0; ci<CPW; ++ci) {
          int c = wv + ci*NW;
          if (c < nch)
            acc[ci][at] = __builtin_amdgcn_mfma_f32_16x16x32_bf16(af, bf[ci], acc[ci][at], 0,0,0);
        }
      }
    }
    __builtin_amdgcn_s_setprio(0);
    asm volatile("s_barrier" ::: "memory");       // all done reading this buffer
  }

  // K-tail A-frags (shared across chunks)
  s8v aftA[AT]; bool tv0=false, tv1=false;
  if constexpr ((C & 31) != 0) {
    int kg = (C & ~31) + ko;
    tv0 = (kg+4 <= C); tv1 = (kg+8 <= C);
    #pragma unroll
    for (int at=0;at<AT;++at) aftA[at] = ldfrag_m(aRow[at] + (C & ~31) + ko, tv0, tv1);
  }

  float sumE[AT][4];
  #pragma unroll
  for (int at=0;at<AT;++at) { sumE[at][0]=0.f; sumE[at][1]=0.f; sumE[at][2]=0.f; sumE[at][3]=0.f; }

  #pragma unroll
  for (int ci=0; ci<CPW; ++ci) {
    int c = wv + ci*NW;
    if (c < nch) {
      int mu = c*16 + col; bool vm = mu < Ms;
      int mus = vm ? mu : 0;
      if constexpr ((C & 31) != 0) {
        s8v bft = ldfrag_m(sliceM + (size_t)mus*C + (C & ~31) + ko, tv0, tv1);
        #pragma unroll
        for (int at=0;at<AT;++at)
          acc[ci][at] = __builtin_amdgcn_mfma_f32_16x16x32_bf16(aftA[at], bft, acc[ci][at], 0,0,0);
      }
      float invBm = invMsl[mus];
      int myq = mus/NG; int my = y0 + myq; int mx = mus - myq*NG;
      #pragma unroll
      for (int at=0; at<AT; ++at) {
        int gzi = at/XT;
        bool lv = (jg*JM+gzi <= 2*R) && ((unsigned)(gz0+gzi) < (unsigned)NG);
        bool mzEq = lv && (gz0+gzi == mz);
        #pragma unroll
        for (int jj=0;jj<4;++jj) {
          int x = (at%XT)*16 + grp*4 + jj;
          int row = at*16 + grp*4 + jj;
          float sim = acc[ci][at][jj] * invAS[row] * invBm;
          bool ok = vm && lv && (x < NG) && (mx - x <= R) && (x - mx <= R);
          if (ok) {
            sumE[at][jj] += __expf(sim);
            if (mzEq && my==gy && mx==x)
              alnG[(size_t)b*N + ((size_t)(gz0+gzi)*NG + gy)*NG + x] = sim;
          }
        }
      }
    }
  }

  #pragma unroll
  for (int at=0;at<AT;++at) {
    #pragma unroll
    for (int jj=0;jj<4;++jj) {
      float v = sumE[at][jj];
      v += __shfl_xor(v,1); v += __shfl_xor(v,2); v += __shfl_xor(v,4); v += __shfl_xor(v,8);
      if (col==0 && v != 0.f) atomicAdd(&sumS[at*16 + grp*4 + jj], v);
    }
  }
  __syncthreads();
  for (int i = tid; i < NROWS; i += TPB) {
    int at = i >> 4, sub = i & 15;
    int gzi = at/XT, x = (at%XT)*16 + sub;
    bool lvr = (jg*JM+gzi <= 2*R) && ((unsigned)(gz0+gzi) < (unsigned)NG) && (x < NG);
    float v = sumS[i];
    if (lvr && v != 0.f)
      atomicAdd(&sumG[(size_t)b*N + ((size_t)(gz0+gzi)*NG + gy)*NG + x], v);
  }
}

__global__ void epilogue_kernel(const float* __restrict__ sumG, const float* __restrict__ alnG,
                                const float* __restrict__ sw, float* __restrict__ out) {
  constexpr int N3 = 54000, N5 = 11664, N9 = 2000;
  constexpr int TOT = N3 + N5 + N9;
  __shared__ float wred[4];
  int idx = blockIdx.x*256 + threadIdx.x;
  float w0 = sw[0], w1 = sw[1], w2 = sw[2];
  float mx = fmaxf(w0, fmaxf(w1, w2));
  float e0 = __expf(w0-mx), e1 = __expf(w1-mx), e2 = __expf(w2-mx);
  float ise = 1.0f/(e0+e1+e2);
  float c = 0.f;
  if (idx < TOT) {
    float coef;
    if (idx < N3)            coef = e0*ise/(float)N3;
    else if (idx < N3+N5)    coef = e1*ise/(float)N5;
    else                     coef = e2*ise/(float)N9;
    c = (__logf(sumG[idx]) - alnG[idx]) * coef;
  }
  #pragma unroll
  for (int o=32;o;o>>=1) c += __shfl_xor(c, o);
  if ((threadIdx.x & 63)==0) wred[threadIdx.x>>6] = c;
  __syncthreads();
  if (threadIdx.x==0) {
    float s = wred[0]+wred[1]+wred[2]+wred[3];
    if (s != 0.f) atomicAdd(out, s);
  }
}

static inline int cdiv(long long a, int b) { return (int)((a + b - 1) / b); }

template<int P, int R, int JM, int XT, int TPB, int KB, int NCHMAX, int CPW, int CCH>
static void run_scale(const ushort* Yf, const ushort* Ym, ushort* pkF, ushort* pkM,
                      float* invPF, float* invPM, float* sumG, float* alnG, hipStream_t s) {
  constexpr int NG=90/P, N=NG*NG*NG, C=12*P*P*P;
  constexpr int NJG=(2*R+1+JM-1)/JM;
  packn_kernel<P,CCH><<<2*NG*NG, 256, 0, s>>>(Yf, pkF);
  packn_kernel<P,CCH><<<2*NG*NG, 256, 0, s>>>(Ym, pkM);
  normk<C><<<2*N, 64, 0, s>>>(pkF, invPF);
  normk<C><<<2*N, 64, 0, s>>>(pkM, invPM);
  loss_kernel<P,R,JM,XT,TPB,KB,NCHMAX,CPW><<<2*NG*NG*NJG, TPB, 0, s>>>(
      pkF, pkM, invPF, invPM, sumG, alnG);
}

extern "C" void kernel_launch(void* const* d_in, const int* in_sizes, int n_in,
                              void* d_out, int out_size, void* d_ws, size_t ws_size,
                              hipStream_t stream) {
  const float* fixedI  = (const float*)d_in[0];
  const float* movingI = (const float*)d_in[1];
  const float* scale_w = (const float*)d_in[2];
  float* out = (float*)d_out;

  uint8_t* w = (uint8_t*)d_ws;
  float*  smallb = (float*)w;                    // [0]=mv_f [1]=mv_m
  float*  sumG  = (float*)(w + 4096);
  float*  alnG  = sumG + 67664;
  float*  invPF = alnG + 67664;
  float*  invPM = invPF + 67664;
  uint8_t* big = w + (2u<<20);
  float*  A   = (float*)big;                      // 70MB f32 scratch
  float*  Bf  = (float*)(big + 69984000);         // 70MB f32 scratch / PK region
  ushort* pkF = (ushort*)Bf;
  ushort* pkM = pkF + 17496000;
  ushort* Ybf_f = (ushort*)(big + 2*69984000ull);
  ushort* Ybf_m = Ybf_f + 17496000;

  hipMemsetAsync(w, 0, 4096 + 67664*4, stream);
  hipMemsetAsync(d_out, 0, sizeof(float), stream);

  const int gE = cdiv(17496000, 256);
  const int gV = cdiv(1458000, 256);

  diff2z_kernel<<<gE,256,0,stream>>>(fixedI, Bf);
  boxy_kernel<<<gE,256,0,stream>>>(Bf, A);
  boxxmin_kernel<<<gV,256,0,stream>>>(A, Bf, smallb+0);
  finalize_kernel<<<gV,256,0,stream>>>(Bf, Ybf_f, smallb+0);

  diff2z_kernel<<<gE,256,0,stream>>>(movingI, A);
  boxy_kernel<<<gE,256,0,stream>>>(A, Bf);
  boxxmin_kernel<<<gV,256,0,stream>>>(Bf, A, smallb+1);
  finalize_kernel<<<gV,256,0,stream>>>(A, Ybf_m, smallb+1);

  // (P,R,JM,XT,TPB,KB,NCHMAX,CPW,CCH)
  run_scale<3,3,2,2,256,1,14,4,12>(Ybf_f, Ybf_m, pkF, pkM, invPF,         invPM,         sumG,         alnG,         stream);
  run_scale<5,2,3,2,256,1, 6,2, 6>(Ybf_f, Ybf_m, pkF, pkM, invPF + 54000, invPM + 54000, sumG + 54000, alnG + 54000, stream);
  run_scale<9,1,1,1,128,8, 2,1, 2>(Ybf_f, Ybf_m, pkF, pkM, invPF + 65664, invPM + 65664, sumG + 65664, alnG + 65664, stream);

  epilogue_kernel<<<cdiv(67664,256),256,0,stream>>>(sumG, alnG, scale_w, out);
}

// Round 12
// 951.070 us; speedup vs baseline: 2.0183x; 1.1056x over previous
//
#include <hip/hip_runtime.h>
#include <hip/hip_bf16.h>
#include <math.h>

#define VOL 729000
#define SL  8100
#define RW  90

typedef __attribute__((ext_vector_type(8))) short s8v;
typedef __attribute__((ext_vector_type(4))) float f32x4;

__device__ __constant__ int c_o1[12][3] = {
  {0,0,-2},{0,-2,0},{0,-2,0},{0,0,2},{0,0,2},{2,0,0},{2,0,0},{2,0,0},{0,2,0},{0,2,0},{0,2,0},{0,2,0}
};
__device__ __constant__ int c_o2[12][3] = {
  {-2,0,0},{-2,0,0},{0,0,-2},{-2,0,0},{0,-2,0},{0,0,-2},{0,-2,0},{0,0,2},{-2,0,0},{0,0,-2},{0,0,2},{2,0,0}
};

__device__ __forceinline__ int clampi(int v, int lo, int hi){ return v<lo?lo:(v>hi?hi:v); }

typedef __attribute__((address_space(3))) uint lds_uint;
typedef __attribute__((address_space(1))) uint glb_uint;
__device__ __forceinline__ void gl_lds16(const ushort* g, ushort* l) {
  __builtin_amdgcn_global_load_lds((const glb_uint*)g, (lds_uint*)l, 16, 0, 0);
}
__device__ __forceinline__ float bf2f(uint u) { return __uint_as_float(u << 16); }
__device__ __forceinline__ ushort f2bf(float f) {
  __hip_bfloat16 h = __float2bfloat16(f);
  return *(ushort*)&h;
}

// fused diff2+zbox+ybox: block = (b,t,z) plane; zboxed tile in LDS, then y-box.
__global__ __launch_bounds__(256) void zy_kernel(const float* __restrict__ img,
                                                 float* __restrict__ out) {
  __shared__ float zb[8100];
  int nwg = gridDim.x;
  int q = nwg >> 3, r8 = nwg & 7;
  int xcd = blockIdx.x & 7, sidx = blockIdx.x >> 3;
  int lid = (xcd < r8 ? xcd*(q+1) : r8*(q+1) + (xcd - r8)*q) + sidx;
  int z = lid % 90; int bc = lid / 90; int t = bc % 12; int b = bc / 12;
  const float* im = img + (size_t)b*VOL;
  int o1z=c_o1[t][0], o1y=c_o1[t][1], o1x=c_o1[t][2];
  int o2z=c_o2[t][0], o2y=c_o2[t][1], o2x=c_o2[t][2];
  int tid = threadIdx.x;
  int z1a[5], z2a[5];
  #pragma unroll
  for (int d=0; d<5; ++d) {
    int zz = clampi(z+d-2,0,89);
    z1a[d] = clampi(zz+o1z,0,89);
    z2a[d] = clampi(zz+o2z,0,89);
  }
  for (int i = tid; i < 8100; i += 256) {
    int y = i/90, x = i - (i/90)*90;
    int y1 = clampi(y+o1y,0,89), x1 = clampi(x+o1x,0,89);
    int y2 = clampi(y+o2y,0,89), x2 = clampi(x+o2x,0,89);
    float s = 0.f;
    #pragma unroll
    for (int d=0; d<5; ++d) {
      float dv = im[z1a[d]*SL + y1*RW + x1] - im[z2a[d]*SL + y2*RW + x2];
      s += dv*dv;
    }
    zb[i] = s;
  }
  __syncthreads();
  float* ob = out + (size_t)bc*VOL + (size_t)z*SL;
  for (int i = tid; i < 8100; i += 256) {
    int y = i/90; int x = i - y*90;
    float s = 0.f;
    #pragma unroll
    for (int d=-2; d<=2; ++d) { int yc = clampi(y+d,0,89); s += zb[yc*90 + x]; }
    ob[i] = s;
  }
}

// x box (/125), channel min, pre = ssd-min -> bf16; accumulate sum of per-voxel mv (f32)
__global__ void boxxmin_kernel(const float* __restrict__ in, ushort* __restrict__ outPre,
                               float* __restrict__ mvsum) {
  __shared__ float red;
  if (threadIdx.x == 0) red = 0.f;
  __syncthreads();
  int idx = blockIdx.x*256 + threadIdx.x;
  float mv = 0.f;
  if (idx < 2*VOL) {
    int b = idx / VOL; int vox = idx % VOL;
    int z = vox / SL; int r = vox % SL; int y = r / RW; int x = r % RW;
    const float* base = in + (size_t)b*12*VOL + (size_t)z*SL + (size_t)y*RW;
    float s[12]; float mn = 3.4e38f;
    #pragma unroll
    for (int c=0;c<12;++c) {
      const float* pc = base + (size_t)c*VOL;
      float t = 0.f;
      #pragma unroll
      for (int d=-2;d<=2;++d) { int xc = clampi(x+d,0,89); t += pc[xc]; }
      t *= (1.0f/125.0f);
      s[c] = t; mn = fminf(mn, t);
    }
    ushort* ob = outPre + (size_t)b*12*VOL + vox;
    #pragma unroll
    for (int c=0;c<12;++c) { float pre = s[c]-mn; ob[(size_t)c*VOL] = f2bf(pre); mv += pre; }
    mv *= (1.0f/12.0f);
  }
  #pragma unroll
  for (int o=32;o;o>>=1) mv += __shfl_xor(mv, o);
  if ((threadIdx.x & 63)==0 && mv != 0.f) atomicAdd(&red, mv);
  __syncthreads();
  if (threadIdx.x==0) atomicAdd(mvsum, red);
}

// bf16 pre -> bf16 mind: exp(-pre / clip(mean_c(pre), mm*1e-3, mm*1e3))
__global__ void finalize_kernel(const ushort* __restrict__ pre, ushort* __restrict__ out,
                                const float* __restrict__ mvsum) {
  int idx = blockIdx.x*256 + threadIdx.x;
  if (idx >= 2*VOL) return;
  int b = idx / VOL; int vox = idx % VOL;
  const ushort* base = pre + (size_t)b*12*VOL + vox;
  ushort* ob = out + (size_t)b*12*VOL + vox;
  float s[12]; float mv = 0.f;
  #pragma unroll
  for (int c=0;c<12;++c) { s[c] = bf2f(base[(size_t)c*VOL]); mv += s[c]; }
  mv *= (1.0f/12.0f);
  float mm = *mvsum * (1.0f/1458000.0f);
  float mvc = fminf(fmaxf(mv, mm*0.001f), mm*1000.0f);
  float inv = 1.0f / mvc;
  #pragma unroll
  for (int c=0;c<12;++c) ob[(size_t)c*VOL] = f2bf(__expf(-s[c]*inv));
}

template<int P, int CCH>
__global__ __launch_bounds__(256) void packn_kernel(const ushort* __restrict__ Ybf,
                                                    ushort* __restrict__ pk) {
  constexpr int NG=90/P, N=NG*NG*NG, C=12*P*P*P;
  constexpr int P2=P*P, P3=P*P*P;
  constexpr int ROWS = CCH*P2;
  constexpr int HALF = CCH*P3/2;
  __shared__ uint slabU[ROWS*48];
  int blk = blockIdx.x;
  int gy = blk % NG; int t1 = blk / NG; int gz = t1 % NG; int b = t1 / NG;
  int tid = threadIdx.x;
  size_t obase = ((size_t)b*N + ((size_t)gz*NG + gy)*NG) * C;
  for (int c0 = 0; c0 < 12; c0 += CCH) {
    if (c0) __syncthreads();
    for (int i = tid; i < ROWS*45; i += 256) {
      int r = i/45, xu = i - r*45;
      int c = c0 + r/P2; int rr = r % P2; int dz = rr/P, dy = rr - dz*P;
      const ushort* src = Ybf + ((size_t)(b*12 + c)*VOL + (size_t)(gz*P+dz)*SL + (size_t)(gy*P+dy)*RW);
      slabU[r*48 + xu] = *(const uint*)(src + 2*xu);
    }
    __syncthreads();
    const ushort* slab = (const ushort*)slabU;
    for (int i = tid; i < NG*HALF; i += 256) {
      int d = i/HALF, j2 = i - d*HALF;
      int k = 2*j2;
      int cc = k/P3; int rem = k - cc*P3;
      int dz = rem/P2; int r2 = rem - dz*P2; int dy = r2/P; int dx = r2 - dy*P;
      uint lo = slab[((cc*P + dz)*P + dy)*96 + d*P + dx];
      int k1 = k+1;
      int cc1 = k1/P3; int rem1 = k1 - cc1*P3;
      int dz1 = rem1/P2; int r21 = rem1 - dz1*P2; int dy1 = r21/P; int dx1 = r21 - dy1*P;
      uint hi = slab[((cc1*P + dz1)*P + dy1)*96 + d*P + dx1];
      *(uint*)(pk + obase + (size_t)d*C + c0*P3 + k) = lo | (hi << 16);
    }
  }
}

template<int C>
__global__ __launch_bounds__(64) void normk(const ushort* __restrict__ pk,
                                            float* __restrict__ inv) {
  int d = blockIdx.x; int lane = threadIdx.x;
  const uint* p = (const uint*)(pk + (size_t)d*C);
  float ss = 0.f;
  for (int i = lane; i < C/2; i += 64) {
    uint u = p[i];
    float a = bf2f(u & 0xffffu), bb = bf2f(u >> 16);
    ss += a*a + bb*bb;
  }
  #pragma unroll
  for (int o=32;o;o>>=1) ss += __shfl_xor(ss, o);
  if (lane==0) inv[d] = 1.0f / fmaxf(sqrtf(ss), 1e-12f);
}

union FragU { s8v s; uint u[4]; };
__device__ __forceinline__ s8v ldfrag_m(const ushort* p, bool v0, bool v1) {
  FragU f;
  if (v0) { uint2 a = *(const uint2*)p;     f.u[0]=a.x; f.u[1]=a.y; } else { f.u[0]=0; f.u[1]=0; }
  if (v1) { uint2 b = *(const uint2*)(p+4); f.u[2]=b.x; f.u[3]=b.y; } else { f.u[2]=0; f.u[3]=0; }
  return f.s;
}

// Merged-line loss (R11 structure), higher-occupancy wave configs.
template<int P, int R, int JM, int XT, int TPB, int KB, int NCHMAX, int CPW>
__global__ __launch_bounds__(TPB) void loss_kernel(
    const ushort* __restrict__ pkF, const ushort* __restrict__ pkM,
    const float* __restrict__ invF, const float* __restrict__ invM,
    float* __restrict__ sumG, float* __restrict__ alnG) {
  constexpr int NG=90/P, N=NG*NG*NG, C=12*P*P*P;
  constexpr int NW=TPB/64;
  constexpr int AT=JM*XT;
  constexpr int KS4=(C & ~31)/32;
  constexpr int NPH=(KS4+KB-1)/KB;
  constexpr int NROWS=AT*16;
  constexpr int NJG=(2*R+1+JM-1)/JM;
  constexpr int SLOTS=(AT+NCHMAX)*KB;
  constexpr int TOTS=((SLOTS+NW-1)/NW)*NW;
  constexpr int TCNT=TOTS/NW;
  static_assert(XT*16 >= NG, "x tiles cover line");
  static_assert(CPW*NW >= NCHMAX, "chunk coverage");
  __shared__ float sumS[NROWS];
  __shared__ float invAS[NROWS];
  __shared__ __align__(16) ushort bP[2][SLOTS*512];

  int nwg = gridDim.x;
  int q = nwg >> 3, r8 = nwg & 7;
  int xcd = blockIdx.x & 7, sidx = blockIdx.x >> 3;
  int lid = (xcd < r8 ? xcd*(q+1) : r8*(q+1) + (xcd - r8)*q) + sidx;
  int jg = lid % NJG; int t1 = lid / NJG;
  int gy = t1 % NG; t1 /= NG;
  int mz = t1 % NG; int b = t1 / NG;
  int gz0 = mz - R + jg*JM;
  bool any = false;
  #pragma unroll
  for (int g=0; g<JM; ++g)
    any |= (jg*JM+g <= 2*R) && ((unsigned)(gz0+g) < (unsigned)NG);
  if (!any) return;

  int tid = threadIdx.x; int lane = tid & 63; int wv = tid >> 6;
  int col = lane & 15, grp = lane >> 4;
  const int ko = grp*8;

  const ushort* aRow[AT];
  #pragma unroll
  for (int at=0; at<AT; ++at) {
    int gzi = at/XT, xt = at%XT;
    int gzc = clampi(gz0+gzi, 0, NG-1);
    int xd = xt*16 + col; if (xd > NG-1) xd = NG-1;
    aRow[at] = pkF + ((size_t)b*N + ((size_t)gzc*NG + gy)*NG + xd) * C;
  }
  for (int i = tid; i < NROWS; i += TPB) {
    sumS[i] = 0.f;
    int at = i >> 4, sub = i & 15;
    int gzi = at/XT, x = (at%XT)*16 + sub;
    bool lvr = (jg*JM+gzi <= 2*R) && ((unsigned)(gz0+gzi) < (unsigned)NG) && (x < NG);
    invAS[i] = lvr ? invF[(size_t)b*N + ((size_t)(gz0+gzi)*NG + gy)*NG + x] : 0.f;
  }

  int y0 = max(gy-R,0), y1 = min(gy+R,NG-1);
  int wy = y1-y0+1;
  int Ms = wy*NG;
  int nch = (Ms+15)>>4;
  const ushort* sliceM = pkM + ((size_t)b*N + ((size_t)mz*NG + y0)*NG) * C;
  const float* invMsl  = invM + (size_t)b*N + ((size_t)mz*NG + y0)*NG;

  auto stage = [&](int ph, ushort* dst) {
    int tb = ph*KB;
    #pragma unroll
    for (int k = 0; k < TCNT; ++k) {
      int i2 = wv + k*NW;
      int ii = i2 < SLOTS ? i2 : SLOTS-1;
      int slot = ii / KB, s = ii - slot*KB;
      int ks = tb + s; if (ks >= KS4) ks = KS4-1;
      const ushort* src;
      if (slot < AT) {
        src = aRow[slot] + (size_t)ks*32 + ko;
      } else {
        int c = slot - AT; if (c > nch-1) c = nch-1;
        int di = c*16 + col; if (di > Ms-1) di = Ms-1;
        src = sliceM + (size_t)di*C + (size_t)ks*32 + ko;
      }
      gl_lds16(src, dst + ii*512);
    }
  };

  stage(0, bP[0]);
  __syncthreads();

  f32x4 acc[CPW][AT];
  #pragma unroll
  for (int ci=0;ci<CPW;++ci)
    #pragma unroll
    for (int at=0;at<AT;++at) acc[ci][at] = (f32x4){0.f,0.f,0.f,0.f};

  for (int ph = 0; ph < NPH; ++ph) {
    if (ph+1 < NPH) {
      stage(ph+1, bP[(ph+1)&1]);
      asm volatile("s_waitcnt vmcnt(%0)" :: "i"(TCNT) : "memory");
    } else {
      asm volatile("s_waitcnt vmcnt(0)" ::: "memory");
    }
    __builtin_amdgcn_sched_barrier(0);
    asm volatile("s_barrier" ::: "memory");
    const ushort* buf = bP[ph&1];
    __builtin_amdgcn_s_setprio(1);
    #pragma unroll
    for (int s = 0; s < KB; ++s) {
      int ks = ph*KB + s;
      if (ks >= KS4) break;
      s8v bf[CPW];
      #pragma unroll
      for (int ci=0; ci<CPW; ++ci) {
        int c = wv + ci*NW;
        if (c < nch) bf[ci] = *(const s8v*)(buf + ((AT + c)*KB + s)*512 + lane*8);
      }
      #pragma unroll
      for (int at=0; at<AT; ++at) {
        s8v af = *(const s8v*)(buf + (at*KB + s)*512 + lane*8);
        #pragma unroll
        for (int ci=0; ci<CPW; ++ci) {
          int c = wv + ci*NW;
          if (c < nch)
            acc[ci][at] = __builtin_amdgcn_mfma_f32_16x16x32_bf16(af, bf[ci], acc[ci][at], 0,0,0);
        }
      }
    }
    __builtin_amdgcn_s_setprio(0);
    asm volatile("s_barrier" ::: "memory");
  }

  s8v aftA[AT]; bool tv0=false, tv1=false;
  if constexpr ((C & 31) != 0) {
    int kg = (C & ~31) + ko;
    tv0 = (kg+4 <= C); tv1 = (kg+8 <= C);
    #pragma unroll
    for (int at=0;at<AT;++at) aftA[at] = ldfrag_m(aRow[at] + (C & ~31) + ko, tv0, tv1);
  }

  float sumE[AT][4];
  #pragma unroll
  for (int at=0;at<AT;++at) { sumE[at][0]=0.f; sumE[at][1]=0.f; sumE[at][2]=0.f; sumE[at][3]=0.f; }

  #pragma unroll
  for (int ci=0; ci<CPW; ++ci) {
    int c = wv + ci*NW;
    if (c < nch) {
      int mu = c*16 + col; bool vm = mu < Ms;
      int mus = vm ? mu : 0;
      if constexpr ((C & 31) != 0) {
        s8v bft = ldfrag_m(sliceM + (size_t)mus*C + (C & ~31) + ko, tv0, tv1);
        #pragma unroll
        for (int at=0;at<AT;++at)
          acc[ci][at] = __builtin_amdgcn_mfma_f32_16x16x32_bf16(aftA[at], bft, acc[ci][at], 0,0,0);
      }
      float invBm = invMsl[mus];
      int myq = mus/NG; int my = y0 + myq; int mx = mus - myq*NG;
      #pragma unroll
      for (int at=0; at<AT; ++at) {
        int gzi = at/XT;
        bool lv = (jg*JM+gzi <= 2*R) && ((unsigned)(gz0+gzi) < (unsigned)NG);
        bool mzEq = lv && (gz0+gzi == mz);
        #pragma unroll
        for (int jj=0;jj<4;++jj) {
          int x = (at%XT)*16 + grp*4 + jj;
          int row = at*16 + grp*4 + jj;
          float sim = acc[ci][at][jj] * invAS[row] * invBm;
          bool ok = vm && lv && (x < NG) && (mx - x <= R) && (x - mx <= R);
          if (ok) {
            sumE[at][jj] += __expf(sim);
            if (mzEq && my==gy && mx==x)
              alnG[(size_t)b*N + ((size_t)(gz0+gzi)*NG + gy)*NG + x] = sim;
          }
        }
      }
    }
  }

  #pragma unroll
  for (int at=0;at<AT;++at) {
    #pragma unroll
    for (int jj=0;jj<4;++jj) {
      float v = sumE[at][jj];
      v += __shfl_xor(v,1); v += __shfl_xor(v,2); v += __shfl_xor(v,4); v += __shfl_xor(v,8);
      if (col==0 && v != 0.f) atomicAdd(&sumS[at*16 + grp*4 + jj], v);
    }
  }
  __syncthreads();
  for (int i = tid; i < NROWS; i += TPB) {
    int at = i >> 4, sub = i & 15;
    int gzi = at/XT, x = (at%XT)*16 + sub;
    bool lvr = (jg*JM+gzi <= 2*R) && ((unsigned)(gz0+gzi) < (unsigned)NG) && (x < NG);
    float v = sumS[i];
    if (lvr && v != 0.f)
      atomicAdd(&sumG[(size_t)b*N + ((size_t)(gz0+gzi)*NG + gy)*NG + x], v);
  }
}

__global__ void epilogue_kernel(const float* __restrict__ sumG, const float* __restrict__ alnG,
                                const float* __restrict__ sw, float* __restrict__ out) {
  constexpr int N3 = 54000, N5 = 11664, N9 = 2000;
  constexpr int TOT = N3 + N5 + N9;
  __shared__ float wred[4];
  int idx = blockIdx.x*256 + threadIdx.x;
  float w0 = sw[0], w1 = sw[1], w2 = sw[2];
  float mx = fmaxf(w0, fmaxf(w1, w2));
  float e0 = __expf(w0-mx), e1 = __expf(w1-mx), e2 = __expf(w2-mx);
  float ise = 1.0f/(e0+e1+e2);
  float c = 0.f;
  if (idx < TOT) {
    float coef;
    if (idx < N3)            coef = e0*ise/(float)N3;
    else if (idx < N3+N5)    coef = e1*ise/(float)N5;
    else                     coef = e2*ise/(float)N9;
    c = (__logf(sumG[idx]) - alnG[idx]) * coef;
  }
  #pragma unroll
  for (int o=32;o;o>>=1) c += __shfl_xor(c, o);
  if ((threadIdx.x & 63)==0) wred[threadIdx.x>>6] = c;
  __syncthreads();
  if (threadIdx.x==0) {
    float s = wred[0]+wred[1]+wred[2]+wred[3];
    if (s != 0.f) atomicAdd(out, s);
  }
}

static inline int cdiv(long long a, int b) { return (int)((a + b - 1) / b); }

template<int P, int R, int JM, int XT, int TPB, int KB, int NCHMAX, int CPW, int CCH>
static void run_scale(const ushort* Yf, const ushort* Ym, ushort* pkF, ushort* pkM,
                      float* invPF, float* invPM, float* sumG, float* alnG, hipStream_t s) {
  constexpr int NG=90/P, N=NG*NG*NG, C=12*P*P*P;
  constexpr int NJG=(2*R+1+JM-1)/JM;
  packn_kernel<P,CCH><<<2*NG*NG, 256, 0, s>>>(Yf, pkF);
  packn_kernel<P,CCH><<<2*NG*NG, 256, 0, s>>>(Ym, pkM);
  normk<C><<<2*N, 64, 0, s>>>(pkF, invPF);
  normk<C><<<2*N, 64, 0, s>>>(pkM, invPM);
  loss_kernel<P,R,JM,XT,TPB,KB,NCHMAX,CPW><<<2*NG*NG*NJG, TPB, 0, s>>>(
      pkF, pkM, invPF, invPM, sumG, alnG);
}

extern "C" void kernel_launch(void* const* d_in, const int* in_sizes, int n_in,
                              void* d_out, int out_size, void* d_ws, size_t ws_size,
                              hipStream_t stream) {
  const float* fixedI  = (const float*)d_in[0];
  const float* movingI = (const float*)d_in[1];
  const float* scale_w = (const float*)d_in[2];
  float* out = (float*)d_out;

  uint8_t* w = (uint8_t*)d_ws;
  float*  smallb = (float*)w;                    // [0]=mv_f [1]=mv_m
  float*  sumG  = (float*)(w + 4096);
  float*  alnG  = sumG + 67664;
  float*  invPF = alnG + 67664;
  float*  invPM = invPF + 67664;
  uint8_t* big = w + (2u<<20);
  ushort* PK   = (ushort*)big;                   // 70MB: pkF|pkM; preB aliases first 35MB
  ushort* preB = PK;
  float*  Azy  = (float*)(big + 69984000);       // 70MB f32 zy-boxed
  ushort* pkF  = PK;
  ushort* pkM  = PK + 17496000;
  ushort* Ybf_f = (ushort*)(big + 2*69984000ull);
  ushort* Ybf_m = Ybf_f + 17496000;

  hipMemsetAsync(w, 0, 4096 + 67664*4, stream);
  hipMemsetAsync(d_out, 0, sizeof(float), stream);

  const int gV = cdiv(1458000, 256);

  // MIND(fixed): zy -> Azy, boxxmin -> preB(bf16)+mv, finalize -> Ybf_f
  zy_kernel<<<2160,256,0,stream>>>(fixedI, Azy);
  boxxmin_kernel<<<gV,256,0,stream>>>(Azy, preB, smallb+0);
  finalize_kernel<<<gV,256,0,stream>>>(preB, Ybf_f, smallb+0);

  // MIND(moving)
  zy_kernel<<<2160,256,0,stream>>>(movingI, Azy);
  boxxmin_kernel<<<gV,256,0,stream>>>(Azy, preB, smallb+1);
  finalize_kernel<<<gV,256,0,stream>>>(preB, Ybf_m, smallb+1);

  // (P,R,JM,XT,TPB,KB,NCHMAX,CPW,CCH)   [packn overwrites preB region — MIND done]
  run_scale<3,3,2,2,512,1,14,2,12>(Ybf_f, Ybf_m, pkF, pkM, invPF,         invPM,         sumG,         alnG,         stream);
  run_scale<5,2,3,2,384,1, 6,1, 6>(Ybf_f, Ybf_m, pkF, pkM, invPF + 54000, invPM + 54000, sumG + 54000, alnG + 54000, stream);
  run_scale<9,1,1,1,128,8, 2,1, 2>(Ybf_f, Ybf_m, pkF, pkM, invPF + 65664, invPM + 65664, sumG + 65664, alnG + 65664, stream);

  epilogue_kernel<<<cdiv(67664,256),256,0,stream>>>(sumG, alnG, scale_w, out);
}